// Round 1
// baseline (16255.028 us; speedup 1.0000x reference)
//
#include <hip/hip_runtime.h>

// CYK forward, fp32 throughout.
// Strategy:
//  - scores = contract(sum_d outer(lp_d, rp_d), G)  [O-factorization, 8x fewer FLOPs]
//  - mass_d = sum(outer(lp_d,rp_d) * Gsum) fused into the outer-product kernel
//  - feature MLP relu(concat(lf,rf)@Wm) as a tiled fp32 GEMM (dominant cost)
// Layouts:
//  chart_p[b][pos][diag][S=128], chart_f[b][pos][diag][SD=512]
//  O stored in a permuted k-order p = j*256+tid <-> (s,t)=(tid>>1,(tid&1)*64+j)
//  GpT[p][a] / Gsum[p] precomputed in the same permuted order.

constexpr int cB = 64, cL = 32, cNT = 64, cS = 128, cV = 50000;
constexpr int cEMB = 512, cSD = 512, cKP = cS * cS; // 16384
constexpr int CHUNK = 512, DMAX = 31;
constexpr float cEPS = 1e-9f;

// ---------------- G permute + Gsum ----------------
__global__ __launch_bounds__(256) void k_prep_g(const float* __restrict__ G,
                                                float* __restrict__ GpT,
                                                float* __restrict__ Gsum) {
  int p = blockIdx.x * 256 + threadIdx.x;
  int q = p & 255, j = p >> 8;
  int s = q >> 1, t = ((q & 1) << 6) + j;
  int klog = s * cS + t;
  float accum = 0.f;
  for (int a = 0; a < cNT; ++a) {
    float g = G[(size_t)a * cKP + klog];
    GpT[(size_t)p * cNT + a] = g;
    accum += g;
  }
  Gsum[p] = accum;
}

// ---------------- diagonal 0 of chart_p ----------------
__global__ void k_diag(const int* __restrict__ word,
                       const float* __restrict__ preterm,
                       float* __restrict__ chart_p) {
  int row = blockIdx.x; // b*L + l
  int t = threadIdx.x;  // 0..63
  int w = word[row];
  float v = preterm[(size_t)t * cV + w];
  float sum = v;
  #pragma unroll
  for (int off = 1; off < 64; off <<= 1) sum += __shfl_xor(sum, off, 64);
  size_t base = (size_t)row * cL * cS; // diag 0
  chart_p[base + t] = 0.f;
  chart_p[base + 64 + t] = v / (sum + cEPS);
}

// ---------------- shared GEMM micro (64x64 tile, 4x4/thread, kk=16) ----------------
__device__ __forceinline__ void micro16(const float (*As)[68], const float (*Bs)[68],
                                        int r0, int c0, float acc[4][4]) {
  #pragma unroll
  for (int k = 0; k < 16; ++k) {
    float4 a4 = *(const float4*)&As[k][r0];
    float4 b4 = *(const float4*)&Bs[k][c0];
    float ar[4] = {a4.x, a4.y, a4.z, a4.w};
    float br[4] = {b4.x, b4.y, b4.z, b4.w};
    #pragma unroll
    for (int i = 0; i < 4; ++i)
      #pragma unroll
      for (int j = 0; j < 4; ++j)
        acc[i][j] = fmaf(ar[i], br[j], acc[i][j]);
  }
}

// ---------------- feat0 = relu(gather(WE, word) @ Wp + bp) ----------------
__global__ __launch_bounds__(256) void k_feat0(const int* __restrict__ word,
                                               const float* __restrict__ WE,
                                               const float* __restrict__ Wp,
                                               const float* __restrict__ bp,
                                               float* __restrict__ chart_f) {
  __shared__ float As[16][68];
  __shared__ float Bs[16][68];
  int tid = threadIdx.x;
  int rowTile = blockIdx.x * 64;
  int n0 = blockIdx.y * 64;
  int lr = tid >> 2, lk = (tid & 3) << 2;
  int bk = tid >> 4, bn = (tid & 15) << 2;
  int r0 = (tid >> 4) << 2, c0 = (tid & 15) << 2;
  const float* ap = WE + (size_t)word[rowTile + lr] * cEMB;
  float acc[4][4] = {};
  for (int kb = 0; kb < cEMB; kb += 16) {
    float4 av = *(const float4*)(ap + kb + lk);
    float4 bv = *(const float4*)(Wp + (size_t)(kb + bk) * cSD + n0 + bn);
    __syncthreads();
    As[lk + 0][lr] = av.x; As[lk + 1][lr] = av.y;
    As[lk + 2][lr] = av.z; As[lk + 3][lr] = av.w;
    *(float4*)&Bs[bk][bn] = bv;
    __syncthreads();
    micro16(As, Bs, r0, c0, acc);
  }
  float4 bpv = *(const float4*)(bp + n0 + c0);
  float bpr[4] = {bpv.x, bpv.y, bpv.z, bpv.w};
  #pragma unroll
  for (int i = 0; i < 4; ++i) {
    int row = rowTile + r0 + i; // b*L + l
    float4 o;
    o.x = fmaxf(acc[i][0] + bpr[0], 0.f);
    o.y = fmaxf(acc[i][1] + bpr[1], 0.f);
    o.z = fmaxf(acc[i][2] + bpr[2], 0.f);
    o.w = fmaxf(acc[i][3] + bpr[3], 0.f);
    *(float4*)(chart_f + (size_t)row * (cL * cSD) + n0 + c0) = o; // diag 0
  }
}

// ---------------- feats_d = relu(concat(lf,rf) @ Wm + bm) ----------------
__global__ __launch_bounds__(256) void k_feats(const float* __restrict__ chart_f,
                                               const float* __restrict__ Wm,
                                               const float* __restrict__ bm,
                                               float* __restrict__ feats,
                                               int ln, int n) {
  __shared__ float As[16][68];
  __shared__ float Bs[16][68];
  int tid = threadIdx.x;
  int Bn = cB * n;
  int rowTile = blockIdx.x * 64;
  int n0 = blockIdx.y * 64;
  int lr = tid >> 2, lk = (tid & 3) << 2;
  int bk = tid >> 4, bn = (tid & 15) << 2;
  int r0 = (tid >> 4) << 2, c0 = (tid & 15) << 2;
  int row = rowTile + lr;
  int dd = row / Bn;        // 0..D-1  (same for whole tile)
  int r = row - dd * Bn;
  int b = r / n, i = r - b * n;
  const float* lf = chart_f + (((size_t)(b * cL + i)) * cL + dd) * cSD;
  const float* rf = chart_f + (((size_t)(b * cL + i + dd + 1)) * cL + (ln - dd - 2)) * cSD;
  float acc[4][4] = {};
  for (int kb = 0; kb < 2 * cSD; kb += 16) {
    int k = kb + lk;
    const float* apos = (k < cSD) ? (lf + k) : (rf + (k - cSD));
    float4 av = *(const float4*)apos;
    float4 bv = *(const float4*)(Wm + (size_t)(kb + bk) * cSD + n0 + bn);
    __syncthreads();
    As[lk + 0][lr] = av.x; As[lk + 1][lr] = av.y;
    As[lk + 2][lr] = av.z; As[lk + 3][lr] = av.w;
    *(float4*)&Bs[bk][bn] = bv;
    __syncthreads();
    micro16(As, Bs, r0, c0, acc);
  }
  float4 bmv = *(const float4*)(bm + n0 + c0);
  float bmr[4] = {bmv.x, bmv.y, bmv.z, bmv.w};
  #pragma unroll
  for (int i2 = 0; i2 < 4; ++i2) {
    int orow = rowTile + r0 + i2;
    float4 o;
    o.x = fmaxf(acc[i2][0] + bmr[0], 0.f);
    o.y = fmaxf(acc[i2][1] + bmr[1], 0.f);
    o.z = fmaxf(acc[i2][2] + bmr[2], 0.f);
    o.w = fmaxf(acc[i2][3] + bmr[3], 0.f);
    *(float4*)(feats + (size_t)orow * cSD + n0 + c0) = o;
  }
}

// ---------------- outer-product accumulate + masses ----------------
__global__ __launch_bounds__(256) void k_outer(const float* __restrict__ chart_p,
                                               const float* __restrict__ Gsum,
                                               float* __restrict__ O,
                                               float* __restrict__ masses,
                                               int ln, int n, int chunkStart) {
  __shared__ float lp[DMAX][cS];
  __shared__ float rp[DMAX][cS];
  int tid = threadIdx.x;
  int D = ln - 1;
  int Bn = cB * n;
  int row = chunkStart + blockIdx.x;
  int b = row / n, i = row - b * n;
  for (int dd = 0; dd < D; ++dd) {
    if (tid < 128)
      lp[dd][tid] = chart_p[(((size_t)(b * cL + i)) * cL + dd) * cS + tid];
    else
      rp[dd][tid - 128] =
          chart_p[(((size_t)(b * cL + i + dd + 1)) * cL + (ln - dd - 2)) * cS + (tid - 128)];
  }
  __syncthreads();
  float gs[64];
  #pragma unroll
  for (int j = 0; j < 64; ++j) gs[j] = Gsum[j * 256 + tid];
  float acc[64];
  #pragma unroll
  for (int j = 0; j < 64; ++j) acc[j] = 0.f;
  int s = tid >> 1, t0 = (tid & 1) << 6;
  for (int dd = 0; dd < D; ++dd) {
    float lps = lp[dd][s];
    float m = 0.f;
    #pragma unroll
    for (int qq = 0; qq < 16; ++qq) {
      float4 r4 = *(const float4*)&rp[dd][t0 + qq * 4];
      float rr[4] = {r4.x, r4.y, r4.z, r4.w};
      #pragma unroll
      for (int e = 0; e < 4; ++e) {
        float o = lps * rr[e];
        acc[qq * 4 + e] += o;
        m = fmaf(o, gs[qq * 4 + e], m);
      }
    }
    #pragma unroll
    for (int off = 32; off > 0; off >>= 1) m += __shfl_down(m, off, 64);
    if ((tid & 63) == 0) atomicAdd(&masses[(size_t)dd * Bn + row], m);
  }
  float* op = O + (size_t)blockIdx.x * cKP;
  #pragma unroll
  for (int j = 0; j < 64; ++j) op[j * 256 + tid] = acc[j];
}

// ---------------- scores GEMM: O(perm) @ GpT, k-split with atomics ----------------
__global__ __launch_bounds__(256) void k_scores(const float* __restrict__ O,
                                                const float* __restrict__ GpT,
                                                float* __restrict__ scores,
                                                int chunkStart) {
  __shared__ float As[16][68];
  __shared__ float Bs[16][68];
  int tid = threadIdx.x;
  int rowTileL = blockIdx.x * 64; // chunk-local
  int kstart = blockIdx.y * 2048;
  int lr = tid >> 2, lk = (tid & 3) << 2;
  int bk = tid >> 4, bn = (tid & 15) << 2;
  int r0 = (tid >> 4) << 2, c0 = (tid & 15) << 2;
  const float* ap = O + (size_t)(rowTileL + lr) * cKP;
  float acc[4][4] = {};
  for (int kb = kstart; kb < kstart + 2048; kb += 16) {
    float4 av = *(const float4*)(ap + kb + lk);
    float4 bv = *(const float4*)(GpT + (size_t)(kb + bk) * cNT + bn);
    __syncthreads();
    As[lk + 0][lr] = av.x; As[lk + 1][lr] = av.y;
    As[lk + 2][lr] = av.z; As[lk + 3][lr] = av.w;
    *(float4*)&Bs[bk][bn] = bv;
    __syncthreads();
    micro16(As, Bs, r0, c0, acc);
  }
  #pragma unroll
  for (int i = 0; i < 4; ++i)
    #pragma unroll
    for (int j = 0; j < 4; ++j)
      atomicAdd(&scores[(size_t)(chunkStart + rowTileL + r0 + i) * cNT + c0 + j], acc[i][j]);
}

// ---------------- normalize p, write chart_p diag ln-1 ----------------
__global__ void k_normp(const float* __restrict__ scores,
                        float* __restrict__ chart_p, int ln, int n) {
  int row = blockIdx.x;
  int tid = threadIdx.x; // 64
  int b = row / n, i = row - b * n;
  float v = scores[(size_t)row * cNT + tid];
  float sum = v;
  #pragma unroll
  for (int off = 1; off < 64; off <<= 1) sum += __shfl_xor(sum, off, 64);
  size_t base = (((size_t)(b * cL + i)) * cL + (ln - 1)) * cS;
  chart_p[base + tid] = v / (sum + cEPS);
  chart_p[base + 64 + tid] = 0.f;
}

// ---------------- combine feats with mass weights, write chart_f diag ln-1 ----------------
__global__ __launch_bounds__(256) void k_combine(const float* __restrict__ feats,
                                                 const float* __restrict__ masses,
                                                 float* __restrict__ chart_f,
                                                 int ln, int n) {
  __shared__ float lm[DMAX];
  int row = blockIdx.x, tid = threadIdx.x;
  int D = ln - 1, Bn = cB * n;
  int b = row / n, i = row - b * n;
  if (tid < D) lm[tid] = masses[(size_t)tid * Bn + row];
  __syncthreads();
  float msum = 0.f;
  for (int dd = 0; dd < D; ++dd) msum += lm[dd];
  float inv = 1.f / (msum + cEPS);
  size_t outbase = (((size_t)(b * cL + i)) * cL + (ln - 1)) * cSD;
  for (int h = tid; h < cSD; h += 256) {
    float acc = 0.f;
    for (int dd = 0; dd < D; ++dd)
      acc = fmaf(lm[dd], feats[((size_t)dd * Bn + row) * cSD + h], acc);
    chart_f[outbase + h] = acc * inv;
  }
}

// ---------------- root ----------------
__global__ void k_root(const float* __restrict__ chart_p,
                       const float* __restrict__ chart_f,
                       const float* __restrict__ starts,
                       float* __restrict__ out) {
  __shared__ float red[2];
  int b = blockIdx.x, tid = threadIdx.x; // 128
  float v = chart_p[(((size_t)(b * cL)) * cL + (cL - 1)) * cS + tid] * starts[tid];
  #pragma unroll
  for (int off = 1; off < 64; off <<= 1) v += __shfl_xor(v, off, 64);
  if ((tid & 63) == 0) red[tid >> 6] = v;
  __syncthreads();
  float score = red[0] + red[1];
  for (int h = tid; h < cSD; h += 128)
    out[(size_t)b * cSD + h] =
        chart_f[(((size_t)(b * cL)) * cL + (cL - 1)) * cSD + h] * score;
}

extern "C" void kernel_launch(void* const* d_in, const int* in_sizes, int n_in,
                              void* d_out, int out_size, void* d_ws, size_t ws_size,
                              hipStream_t stream) {
  const int* word = (const int*)d_in[0];
  const float* WE = (const float*)d_in[1];
  const float* preterm = (const float*)d_in[2];
  const float* G = (const float*)d_in[3];
  const float* starts = (const float*)d_in[4];
  const float* Wp = (const float*)d_in[5];
  const float* bp = (const float*)d_in[6];
  const float* Wm = (const float*)d_in[7];
  const float* bm = (const float*)d_in[8];
  float* out = (float*)d_out;
  float* ws = (float*)d_ws;

  size_t off = 0;
  float* chart_p = ws + off; off += (size_t)cB * cL * cL * cS;   //  33.5 MB
  float* chart_f = ws + off; off += (size_t)cB * cL * cL * cSD;  // 134.2 MB
  float* GpT     = ws + off; off += (size_t)cKP * cNT;           //   4.2 MB
  float* Gsum    = ws + off; off += cKP;                          //  64 KB
  float* Obuf    = ws + off; off += (size_t)CHUNK * cKP;          //  33.5 MB
  float* feats   = ws + off; off += (size_t)16384 * cSD;          //  33.5 MB
  float* masses  = ws + off; off += 16384;                        //  64 KB
  float* scores  = ws + off; off += (size_t)1984 * cNT;           // 508 KB

  k_prep_g<<<cKP / 256, 256, 0, stream>>>(G, GpT, Gsum);
  k_diag<<<cB * cL, 64, 0, stream>>>(word, preterm, chart_p);
  k_feat0<<<dim3((cB * cL) / 64, cSD / 64), 256, 0, stream>>>(word, WE, Wp, bp, chart_f);

  for (int ln = 2; ln <= cL; ++ln) {
    int n = cL - ln + 1, D = ln - 1, Bn = cB * n;
    hipMemsetAsync(scores, 0, (size_t)Bn * cNT * sizeof(float), stream);
    hipMemsetAsync(masses, 0, (size_t)D * Bn * sizeof(float), stream);
    k_feats<<<dim3((D * Bn) / 64, cSD / 64), 256, 0, stream>>>(chart_f, Wm, bm, feats, ln, n);
    for (int cs = 0; cs < Bn; cs += CHUNK) {
      int rows = (Bn - cs) < CHUNK ? (Bn - cs) : CHUNK;
      k_outer<<<rows, 256, 0, stream>>>(chart_p, Gsum, Obuf, masses, ln, n, cs);
      k_scores<<<dim3(rows / 64, cKP / 2048), 256, 0, stream>>>(Obuf, GpT, scores, cs);
    }
    k_normp<<<Bn, 64, 0, stream>>>(scores, chart_p, ln, n);
    k_combine<<<Bn, 256, 0, stream>>>(feats, masses, chart_f, ln, n);
  }

  k_root<<<cB, 128, 0, stream>>>(chart_p, chart_f, starts, out);
}

// Round 2
// 6593.528 us; speedup vs baseline: 2.4653x; 2.4653x over previous
//
#include <hip/hip_runtime.h>
#include <hip/hip_bf16.h>

// CYK forward. fp32 everywhere except the dominant feature GEMM, which is
// bf16x3 MFMA (hi/lo split: A*B ~= AhBh + AhBl + AlBh, fp32 accumulate).
// chart_f is stored as two bf16 planes (hi, lo); Wm is pre-transposed and
// split once per launch.

typedef __attribute__((ext_vector_type(8))) short short8;  // 8 bf16 = 4 VGPR
typedef __attribute__((ext_vector_type(4))) float f32x4;

constexpr int cB = 64, cL = 32, cNT = 64, cS = 128, cV = 50000;
constexpr int cEMB = 512, cSD = 512, cKP = cS * cS; // 16384
constexpr int DMAX = 31;
constexpr float cEPS = 1e-9f;

__device__ __forceinline__ void split_bf16(float x, __hip_bfloat16& h, __hip_bfloat16& l) {
  h = __float2bfloat16(x);
  l = __float2bfloat16(x - __bfloat162float(h));
}

// ---------------- G permute + Gsum ----------------
__global__ __launch_bounds__(256) void k_prep_g(const float* __restrict__ G,
                                                float* __restrict__ GpT,
                                                float* __restrict__ Gsum) {
  int p = blockIdx.x * 256 + threadIdx.x;
  int q = p & 255, j = p >> 8;
  int s = q >> 1, t = ((q & 1) << 6) + j;
  int klog = s * cS + t;
  float accum = 0.f;
  for (int a = 0; a < cNT; ++a) {
    float g = G[(size_t)a * cKP + klog];
    GpT[(size_t)p * cNT + a] = g;
    accum += g;
  }
  Gsum[p] = accum;
}

// ---------------- WmT hi/lo split: WmT[n][k] = Wm[k][n] ----------------
__global__ __launch_bounds__(256) void k_prep_wmt(const float* __restrict__ Wm,
                                                  __hip_bfloat16* __restrict__ WmTh,
                                                  __hip_bfloat16* __restrict__ WmTl) {
  int idx = blockIdx.x * 256 + threadIdx.x; // n*1024 + k
  int k = idx & 1023, nn = idx >> 10;
  float v = Wm[(size_t)k * cSD + nn];
  __hip_bfloat16 h, l;
  split_bf16(v, h, l);
  WmTh[idx] = h;
  WmTl[idx] = l;
}

// ---------------- diagonal 0 of chart_p ----------------
__global__ void k_diag(const int* __restrict__ word,
                       const float* __restrict__ preterm,
                       float* __restrict__ chart_p) {
  int row = blockIdx.x; // b*L + l
  int t = threadIdx.x;  // 0..63
  int w = word[row];
  float v = preterm[(size_t)t * cV + w];
  float sum = v;
  #pragma unroll
  for (int off = 1; off < 64; off <<= 1) sum += __shfl_xor(sum, off, 64);
  size_t base = (size_t)row * cL * cS; // diag 0
  chart_p[base + t] = 0.f;
  chart_p[base + 64 + t] = v / (sum + cEPS);
}

// ---------------- fp32 GEMM micro (64x64 tile, 4x4/thread, kk=16) ----------------
__device__ __forceinline__ void micro16(const float (*As)[68], const float (*Bs)[68],
                                        int r0, int c0, float acc[4][4]) {
  #pragma unroll
  for (int k = 0; k < 16; ++k) {
    float4 a4 = *(const float4*)&As[k][r0];
    float4 b4 = *(const float4*)&Bs[k][c0];
    float ar[4] = {a4.x, a4.y, a4.z, a4.w};
    float br[4] = {b4.x, b4.y, b4.z, b4.w};
    #pragma unroll
    for (int i = 0; i < 4; ++i)
      #pragma unroll
      for (int j = 0; j < 4; ++j)
        acc[i][j] = fmaf(ar[i], br[j], acc[i][j]);
  }
}

// ---------------- feat0 = relu(gather(WE, word) @ Wp + bp) -> hi/lo planes ----------------
__global__ __launch_bounds__(256) void k_feat0(const int* __restrict__ word,
                                               const float* __restrict__ WE,
                                               const float* __restrict__ Wp,
                                               const float* __restrict__ bp,
                                               __hip_bfloat16* __restrict__ cfh,
                                               __hip_bfloat16* __restrict__ cfl) {
  __shared__ float As[16][68];
  __shared__ float Bs[16][68];
  int tid = threadIdx.x;
  int rowTile = blockIdx.x * 64;
  int n0 = blockIdx.y * 64;
  int lr = tid >> 2, lk = (tid & 3) << 2;
  int bk = tid >> 4, bn = (tid & 15) << 2;
  int r0 = (tid >> 4) << 2, c0 = (tid & 15) << 2;
  const float* ap = WE + (size_t)word[rowTile + lr] * cEMB;
  float acc[4][4] = {};
  for (int kb = 0; kb < cEMB; kb += 16) {
    float4 av = *(const float4*)(ap + kb + lk);
    float4 bv = *(const float4*)(Wp + (size_t)(kb + bk) * cSD + n0 + bn);
    __syncthreads();
    As[lk + 0][lr] = av.x; As[lk + 1][lr] = av.y;
    As[lk + 2][lr] = av.z; As[lk + 3][lr] = av.w;
    *(float4*)&Bs[bk][bn] = bv;
    __syncthreads();
    micro16(As, Bs, r0, c0, acc);
  }
  float4 bpv = *(const float4*)(bp + n0 + c0);
  float bpr[4] = {bpv.x, bpv.y, bpv.z, bpv.w};
  #pragma unroll
  for (int i = 0; i < 4; ++i) {
    int row = rowTile + r0 + i; // b*L + l; cell = row*cL + 0
    size_t base = ((size_t)row * cL) * cSD + n0 + c0;
    #pragma unroll
    for (int e = 0; e < 4; ++e) {
      float v = fmaxf(acc[i][e] + bpr[e], 0.f);
      __hip_bfloat16 h, l;
      split_bf16(v, h, l);
      cfh[base + e] = h;
      cfl[base + e] = l;
    }
  }
}

// ---------------- feats = relu(concat(lf,rf) @ Wm + bm), bf16x3 MFMA ----------------
// 128x128 tile, 4 waves of 64x64, 16x16x32 MFMA, K=1024, 3 plane-combos.
__global__ __launch_bounds__(256) void k_feats_mfma(
    const __hip_bfloat16* __restrict__ cfh, const __hip_bfloat16* __restrict__ cfl,
    const __hip_bfloat16* __restrict__ WmTh, const __hip_bfloat16* __restrict__ WmTl,
    const float* __restrict__ bm, float* __restrict__ feats, int ln, int n, int M) {
  __shared__ short Ash[2 * 128 * 40]; // [plane][m][k], padded stride 40
  __shared__ short Bsh[2 * 128 * 40]; // [plane][n][k]
  int tid = threadIdx.x;
  int Bn = cB * n;
  int rowTile = blockIdx.x * 128;
  int colTile = blockIdx.y * 128;
  int m0 = tid >> 2, kq8 = (tid & 3) * 8;

  long offA[2][2]; // [half][lf/rf], element offsets into chart planes
  #pragma unroll
  for (int h = 0; h < 2; ++h) {
    int row = rowTile + m0 + h * 64;
    if (row >= M) row = M - 1; // pad rows replicate last valid row
    int dd = row / Bn;
    int r = row - dd * Bn;
    int b = r / n, i = r - b * n;
    offA[h][0] = ((long)((b * cL + i) * cL + dd)) * cSD;
    offA[h][1] = ((long)((b * cL + i + dd + 1) * cL + (ln - dd - 2))) * cSD;
  }
  long offB0 = (long)(colTile + m0) * 1024;
  long offB1 = (long)(colTile + m0 + 64) * 1024;

  f32x4 acc[4][4];
  f32x4 zero = {0.f, 0.f, 0.f, 0.f};
  #pragma unroll
  for (int a_ = 0; a_ < 4; ++a_)
    #pragma unroll
    for (int b_ = 0; b_ < 4; ++b_) acc[a_][b_] = zero;

  int lane = tid & 63, wid = tid >> 6;
  int wm = wid >> 1, wn = wid & 1;
  int fr = lane & 15, fq = lane >> 4;

  for (int kb = 0; kb < 1024; kb += 32) {
    int sideL = (kb < cSD) ? 0 : 1;
    int klocal = kb - sideL * cSD;
    int4 vA0h = *(const int4*)(const void*)(cfh + offA[0][sideL] + klocal + kq8);
    int4 vA1h = *(const int4*)(const void*)(cfh + offA[1][sideL] + klocal + kq8);
    int4 vA0l = *(const int4*)(const void*)(cfl + offA[0][sideL] + klocal + kq8);
    int4 vA1l = *(const int4*)(const void*)(cfl + offA[1][sideL] + klocal + kq8);
    int4 vB0h = *(const int4*)(const void*)(WmTh + offB0 + kb + kq8);
    int4 vB1h = *(const int4*)(const void*)(WmTh + offB1 + kb + kq8);
    int4 vB0l = *(const int4*)(const void*)(WmTl + offB0 + kb + kq8);
    int4 vB1l = *(const int4*)(const void*)(WmTl + offB1 + kb + kq8);
    __syncthreads();
    *(int4*)&Ash[(0 * 128 + m0) * 40 + kq8] = vA0h;
    *(int4*)&Ash[(0 * 128 + m0 + 64) * 40 + kq8] = vA1h;
    *(int4*)&Ash[(1 * 128 + m0) * 40 + kq8] = vA0l;
    *(int4*)&Ash[(1 * 128 + m0 + 64) * 40 + kq8] = vA1l;
    *(int4*)&Bsh[(0 * 128 + m0) * 40 + kq8] = vB0h;
    *(int4*)&Bsh[(0 * 128 + m0 + 64) * 40 + kq8] = vB1h;
    *(int4*)&Bsh[(1 * 128 + m0) * 40 + kq8] = vB0l;
    *(int4*)&Bsh[(1 * 128 + m0 + 64) * 40 + kq8] = vB1l;
    __syncthreads();
    short8 af[2][4], bf[2][4];
    #pragma unroll
    for (int pl = 0; pl < 2; ++pl)
      #pragma unroll
      for (int mf = 0; mf < 4; ++mf)
        af[pl][mf] = *(const short8*)&Ash[(pl * 128 + wm * 64 + mf * 16 + fr) * 40 + fq * 8];
    #pragma unroll
    for (int pl = 0; pl < 2; ++pl)
      #pragma unroll
      for (int nf = 0; nf < 4; ++nf)
        bf[pl][nf] = *(const short8*)&Bsh[(pl * 128 + wn * 64 + nf * 16 + fr) * 40 + fq * 8];
    #pragma unroll
    for (int mf = 0; mf < 4; ++mf)
      #pragma unroll
      for (int nf = 0; nf < 4; ++nf) {
        acc[mf][nf] = __builtin_amdgcn_mfma_f32_16x16x32_bf16(af[0][mf], bf[0][nf], acc[mf][nf], 0, 0, 0);
        acc[mf][nf] = __builtin_amdgcn_mfma_f32_16x16x32_bf16(af[0][mf], bf[1][nf], acc[mf][nf], 0, 0, 0);
        acc[mf][nf] = __builtin_amdgcn_mfma_f32_16x16x32_bf16(af[1][mf], bf[0][nf], acc[mf][nf], 0, 0, 0);
      }
  }
  #pragma unroll
  for (int mf = 0; mf < 4; ++mf)
    #pragma unroll
    for (int nf = 0; nf < 4; ++nf) {
      int col = colTile + wn * 64 + nf * 16 + fr;
      float bb = bm[col];
      #pragma unroll
      for (int r = 0; r < 4; ++r) {
        int row = rowTile + wm * 64 + mf * 16 + fq * 4 + r; // C: row=quad*4+reg, col=lane&15
        feats[(size_t)row * cSD + col] = fmaxf(acc[mf][nf][r] + bb, 0.f);
      }
    }
}

// ---------------- outer-product accumulate + masses ----------------
__global__ __launch_bounds__(256) void k_outer(const float* __restrict__ chart_p,
                                               const float* __restrict__ Gsum,
                                               float* __restrict__ O,
                                               float* __restrict__ masses,
                                               int ln, int n, int chunkStart) {
  __shared__ float lp[DMAX][cS];
  __shared__ float rp[DMAX][cS];
  int tid = threadIdx.x;
  int D = ln - 1;
  int Bn = cB * n;
  int row = chunkStart + blockIdx.x;
  int b = row / n, i = row - b * n;
  for (int dd = 0; dd < D; ++dd) {
    if (tid < 128)
      lp[dd][tid] = chart_p[(((size_t)(b * cL + i)) * cL + dd) * cS + tid];
    else
      rp[dd][tid - 128] =
          chart_p[(((size_t)(b * cL + i + dd + 1)) * cL + (ln - dd - 2)) * cS + (tid - 128)];
  }
  __syncthreads();
  float gs[64];
  #pragma unroll
  for (int j = 0; j < 64; ++j) gs[j] = Gsum[j * 256 + tid];
  float acc[64];
  #pragma unroll
  for (int j = 0; j < 64; ++j) acc[j] = 0.f;
  int s = tid >> 1, t0 = (tid & 1) << 6;
  for (int dd = 0; dd < D; ++dd) {
    float lps = lp[dd][s];
    float m = 0.f;
    #pragma unroll
    for (int qq = 0; qq < 16; ++qq) {
      float4 r4 = *(const float4*)&rp[dd][t0 + qq * 4];
      float rr[4] = {r4.x, r4.y, r4.z, r4.w};
      #pragma unroll
      for (int e = 0; e < 4; ++e) {
        float o = lps * rr[e];
        acc[qq * 4 + e] += o;
        m = fmaf(o, gs[qq * 4 + e], m);
      }
    }
    #pragma unroll
    for (int off = 32; off > 0; off >>= 1) m += __shfl_down(m, off, 64);
    if ((tid & 63) == 0) atomicAdd(&masses[(size_t)dd * Bn + row], m);
  }
  float* op = O + (size_t)blockIdx.x * cKP;
  #pragma unroll
  for (int j = 0; j < 64; ++j) op[j * 256 + tid] = acc[j];
}

// ---------------- scores GEMM: O(perm) @ GpT, K-split 32, partial outputs ----------------
__global__ __launch_bounds__(256) void k_scores(const float* __restrict__ O,
                                                const float* __restrict__ GpT,
                                                float* __restrict__ scoresP,
                                                int CH) {
  __shared__ float As[16][68];
  __shared__ float Bs[16][68];
  int tid = threadIdx.x;
  int rowTileL = blockIdx.x * 64; // chunk-local
  int ks = blockIdx.y;            // 0..31
  int kstart = ks * 512;
  int lr = tid >> 2, lk = (tid & 3) << 2;
  int bk = tid >> 4, bn = (tid & 15) << 2;
  int r0 = (tid >> 4) << 2, c0 = (tid & 15) << 2;
  const float* ap = O + (size_t)(rowTileL + lr) * cKP;
  float acc[4][4] = {};
  for (int kb = kstart; kb < kstart + 512; kb += 16) {
    float4 av = *(const float4*)(ap + kb + lk);
    float4 bv = *(const float4*)(GpT + (size_t)(kb + bk) * cNT + bn);
    __syncthreads();
    As[lk + 0][lr] = av.x; As[lk + 1][lr] = av.y;
    As[lk + 2][lr] = av.z; As[lk + 3][lr] = av.w;
    *(float4*)&Bs[bk][bn] = bv;
    __syncthreads();
    micro16(As, Bs, r0, c0, acc);
  }
  #pragma unroll
  for (int i = 0; i < 4; ++i) {
    float4 o = {acc[i][0], acc[i][1], acc[i][2], acc[i][3]};
    *(float4*)&scoresP[((size_t)ks * CH + rowTileL + r0 + i) * cNT + c0] = o;
  }
}

// ---------------- reduce K-split partials, normalize p, write chart_p ----------------
__global__ void k_normp(const float* __restrict__ scoresP,
                        float* __restrict__ chart_p, int ln, int nn, int CH,
                        int chunkStart) {
  int lr = blockIdx.x;
  int tid = threadIdx.x; // 64
  float v = 0.f;
  for (int ks = 0; ks < 32; ++ks)
    v += scoresP[((size_t)ks * CH + lr) * cNT + tid];
  float sum = v;
  #pragma unroll
  for (int off = 1; off < 64; off <<= 1) sum += __shfl_xor(sum, off, 64);
  int row = chunkStart + lr;
  int b = row / nn, i = row - b * nn;
  size_t base = (((size_t)(b * cL + i)) * cL + (ln - 1)) * cS;
  chart_p[base + tid] = v / (sum + cEPS);
  chart_p[base + 64 + tid] = 0.f;
}

// ---------------- combine feats with mass weights -> chart_f hi/lo ----------------
__global__ __launch_bounds__(256) void k_combine(const float* __restrict__ feats,
                                                 const float* __restrict__ masses,
                                                 __hip_bfloat16* __restrict__ cfh,
                                                 __hip_bfloat16* __restrict__ cfl,
                                                 int ln, int n) {
  __shared__ float lm[DMAX];
  int row = blockIdx.x, tid = threadIdx.x;
  int D = ln - 1, Bn = cB * n;
  int b = row / n, i = row - b * n;
  if (tid < D) lm[tid] = masses[(size_t)tid * Bn + row];
  __syncthreads();
  float msum = 0.f;
  for (int dd = 0; dd < D; ++dd) msum += lm[dd];
  float inv = 1.f / (msum + cEPS);
  size_t outbase = (((size_t)(b * cL + i)) * cL + (ln - 1)) * cSD;
  for (int h = tid; h < cSD; h += 256) {
    float acc = 0.f;
    for (int dd = 0; dd < D; ++dd)
      acc = fmaf(lm[dd], feats[((size_t)dd * Bn + row) * cSD + h], acc);
    float v = acc * inv;
    __hip_bfloat16 hh, ll;
    split_bf16(v, hh, ll);
    cfh[outbase + h] = hh;
    cfl[outbase + h] = ll;
  }
}

// ---------------- root ----------------
__global__ void k_root(const float* __restrict__ chart_p,
                       const __hip_bfloat16* __restrict__ cfh,
                       const __hip_bfloat16* __restrict__ cfl,
                       const float* __restrict__ starts,
                       float* __restrict__ out) {
  __shared__ float red[2];
  int b = blockIdx.x, tid = threadIdx.x; // 128
  float v = chart_p[(((size_t)(b * cL)) * cL + (cL - 1)) * cS + tid] * starts[tid];
  #pragma unroll
  for (int off = 1; off < 64; off <<= 1) v += __shfl_xor(v, off, 64);
  if ((tid & 63) == 0) red[tid >> 6] = v;
  __syncthreads();
  float score = red[0] + red[1];
  size_t fbase = (((size_t)(b * cL)) * cL + (cL - 1)) * cSD;
  for (int h = tid; h < cSD; h += 128) {
    float f = __bfloat162float(cfh[fbase + h]) + __bfloat162float(cfl[fbase + h]);
    out[(size_t)b * cSD + h] = f * score;
  }
}

extern "C" void kernel_launch(void* const* d_in, const int* in_sizes, int n_in,
                              void* d_out, int out_size, void* d_ws, size_t ws_size,
                              hipStream_t stream) {
  const int* word = (const int*)d_in[0];
  const float* WE = (const float*)d_in[1];
  const float* preterm = (const float*)d_in[2];
  const float* G = (const float*)d_in[3];
  const float* starts = (const float*)d_in[4];
  const float* Wp = (const float*)d_in[5];
  const float* bp = (const float*)d_in[6];
  const float* Wm = (const float*)d_in[7];
  const float* bm = (const float*)d_in[8];
  float* out = (float*)d_out;
  float* ws = (float*)d_ws;

  size_t off = 0;
  float* chart_p = ws + off; off += (size_t)cB * cL * cL * cS;                 // 33.5 MB
  __hip_bfloat16* cfh = (__hip_bfloat16*)(ws + off); off += (size_t)cB * cL * cL * cSD / 2; // 67.1 MB
  __hip_bfloat16* cfl = (__hip_bfloat16*)(ws + off); off += (size_t)cB * cL * cL * cSD / 2; // 67.1 MB
  float* GpT = ws + off; off += (size_t)cKP * cNT;                             // 4.2 MB
  float* Gsum = ws + off; off += cKP;
  __hip_bfloat16* WmTh = (__hip_bfloat16*)(ws + off); off += (size_t)cSD * 1024 / 2; // 1 MB
  __hip_bfloat16* WmTl = (__hip_bfloat16*)(ws + off); off += (size_t)cSD * 1024 / 2; // 1 MB
  float* feats = ws + off; off += (size_t)16448 * cSD;                         // 33.7 MB
  float* masses = ws + off; off += 16384;

  // Dynamic chunk size so we never exceed ws_size.
  size_t avail = ws_size / sizeof(float) > off ? ws_size / sizeof(float) - off : 0;
  int CH = (int)(avail / (cKP + 32 * cNT));
  if (CH > 512) CH = 512;
  CH &= ~63;
  if (CH < 64) CH = 64;
  float* Obuf = ws + off; off += (size_t)CH * cKP;
  float* scoresP = ws + off; off += (size_t)CH * 32 * cNT;

  k_prep_g<<<cKP / 256, 256, 0, stream>>>(G, GpT, Gsum);
  k_prep_wmt<<<(cSD * 1024) / 256, 256, 0, stream>>>(Wm, WmTh, WmTl);
  k_diag<<<cB * cL, 64, 0, stream>>>(word, preterm, chart_p);
  k_feat0<<<dim3((cB * cL) / 64, cSD / 64), 256, 0, stream>>>(word, WE, Wp, bp, cfh, cfl);

  for (int ln = 2; ln <= cL; ++ln) {
    int n = cL - ln + 1, D = ln - 1, Bn = cB * n;
    int M = D * Bn;
    int padM = (M + 127) & ~127;
    hipMemsetAsync(masses, 0, (size_t)D * Bn * sizeof(float), stream);
    k_feats_mfma<<<dim3(padM / 128, cSD / 128), 256, 0, stream>>>(cfh, cfl, WmTh, WmTl, bm,
                                                                  feats, ln, n, M);
    for (int cs = 0; cs < Bn; cs += CH) {
      int rows = (Bn - cs) < CH ? (Bn - cs) : CH;
      k_outer<<<rows, 256, 0, stream>>>(chart_p, Gsum, Obuf, masses, ln, n, cs);
      k_scores<<<dim3(rows / 64, 32), 256, 0, stream>>>(Obuf, GpT, scoresP, CH);
      k_normp<<<rows, 64, 0, stream>>>(scoresP, chart_p, ln, n, CH, cs);
    }
    k_combine<<<Bn, 256, 0, stream>>>(feats, masses, cfh, cfl, ln, n);
  }

  k_root<<<cB, 128, 0, stream>>>(chart_p, cfh, cfl, starts, out);
}

// Round 4
// 6402.811 us; speedup vs baseline: 2.5387x; 1.0298x over previous
//
#include <hip/hip_runtime.h>
#include <hip/hip_bf16.h>

// CYK forward. p-chain (scores/masses/chart_p) kept fp32 end-to-end (errors
// compound across 31 levels); f-chain GEMM (dominant FLOPs) is bf16x3 MFMA.
// Round 4: fix cross-wave mass reduction (round 3 raced: 4 wave-partials
// need summing — LDS reduce, not plain store). k_scores 128x64/kk=32 kept.

typedef __attribute__((ext_vector_type(8))) short short8;  // 8 bf16 = 4 VGPR
typedef __attribute__((ext_vector_type(4))) float f32x4;

constexpr int cB = 64, cL = 32, cNT = 64, cS = 128, cV = 50000;
constexpr int cEMB = 512, cSD = 512, cKP = cS * cS; // 16384
constexpr int DMAX = 31, KS = 16;
constexpr float cEPS = 1e-9f;

__device__ __forceinline__ void split_bf16(float x, __hip_bfloat16& h, __hip_bfloat16& l) {
  h = __float2bfloat16(x);
  l = __float2bfloat16(x - __bfloat162float(h));
}

// ---------------- G permute + Gsum ----------------
__global__ __launch_bounds__(256) void k_prep_g(const float* __restrict__ G,
                                                float* __restrict__ GpT,
                                                float* __restrict__ Gsum) {
  int p = blockIdx.x * 256 + threadIdx.x;
  int q = p & 255, j = p >> 8;
  int s = q >> 1, t = ((q & 1) << 6) + j;
  int klog = s * cS + t;
  float accum = 0.f;
  for (int a = 0; a < cNT; ++a) {
    float g = G[(size_t)a * cKP + klog];
    GpT[(size_t)p * cNT + a] = g;
    accum += g;
  }
  Gsum[p] = accum;
}

// ---------------- WmT hi/lo split: WmT[n][k] = Wm[k][n] ----------------
__global__ __launch_bounds__(256) void k_prep_wmt(const float* __restrict__ Wm,
                                                  __hip_bfloat16* __restrict__ WmTh,
                                                  __hip_bfloat16* __restrict__ WmTl) {
  int idx = blockIdx.x * 256 + threadIdx.x; // n*1024 + k
  int k = idx & 1023, nn = idx >> 10;
  float v = Wm[(size_t)k * cSD + nn];
  __hip_bfloat16 h, l;
  split_bf16(v, h, l);
  WmTh[idx] = h;
  WmTl[idx] = l;
}

// ---------------- diagonal 0 of chart_p ----------------
__global__ void k_diag(const int* __restrict__ word,
                       const float* __restrict__ preterm,
                       float* __restrict__ chart_p) {
  int row = blockIdx.x; // b*L + l
  int t = threadIdx.x;  // 0..63
  int w = word[row];
  float v = preterm[(size_t)t * cV + w];
  float sum = v;
  #pragma unroll
  for (int off = 1; off < 64; off <<= 1) sum += __shfl_xor(sum, off, 64);
  size_t base = (size_t)row * cL * cS; // diag 0
  chart_p[base + t] = 0.f;
  chart_p[base + 64 + t] = v / (sum + cEPS);
}

// ---------------- fp32 GEMM micro (64x64 tile, 4x4/thread, kk=16) ----------------
__device__ __forceinline__ void micro16(const float (*As)[68], const float (*Bs)[68],
                                        int r0, int c0, float acc[4][4]) {
  #pragma unroll
  for (int k = 0; k < 16; ++k) {
    float4 a4 = *(const float4*)&As[k][r0];
    float4 b4 = *(const float4*)&Bs[k][c0];
    float ar[4] = {a4.x, a4.y, a4.z, a4.w};
    float br[4] = {b4.x, b4.y, b4.z, b4.w};
    #pragma unroll
    for (int i = 0; i < 4; ++i)
      #pragma unroll
      for (int j = 0; j < 4; ++j)
        acc[i][j] = fmaf(ar[i], br[j], acc[i][j]);
  }
}

// ---------------- feat0 = relu(gather(WE, word) @ Wp + bp) -> hi/lo planes ----------------
__global__ __launch_bounds__(256) void k_feat0(const int* __restrict__ word,
                                               const float* __restrict__ WE,
                                               const float* __restrict__ Wp,
                                               const float* __restrict__ bp,
                                               __hip_bfloat16* __restrict__ cfh,
                                               __hip_bfloat16* __restrict__ cfl) {
  __shared__ float As[16][68];
  __shared__ float Bs[16][68];
  int tid = threadIdx.x;
  int rowTile = blockIdx.x * 64;
  int n0 = blockIdx.y * 64;
  int lr = tid >> 2, lk = (tid & 3) << 2;
  int bk = tid >> 4, bn = (tid & 15) << 2;
  int r0 = (tid >> 4) << 2, c0 = (tid & 15) << 2;
  const float* ap = WE + (size_t)word[rowTile + lr] * cEMB;
  float acc[4][4] = {};
  for (int kb = 0; kb < cEMB; kb += 16) {
    float4 av = *(const float4*)(ap + kb + lk);
    float4 bv = *(const float4*)(Wp + (size_t)(kb + bk) * cSD + n0 + bn);
    __syncthreads();
    As[lk + 0][lr] = av.x; As[lk + 1][lr] = av.y;
    As[lk + 2][lr] = av.z; As[lk + 3][lr] = av.w;
    *(float4*)&Bs[bk][bn] = bv;
    __syncthreads();
    micro16(As, Bs, r0, c0, acc);
  }
  float4 bpv = *(const float4*)(bp + n0 + c0);
  float bpr[4] = {bpv.x, bpv.y, bpv.z, bpv.w};
  #pragma unroll
  for (int i = 0; i < 4; ++i) {
    int row = rowTile + r0 + i; // b*L + l; cell = row*cL + 0
    size_t base = ((size_t)row * cL) * cSD + n0 + c0;
    #pragma unroll
    for (int e = 0; e < 4; ++e) {
      float v = fmaxf(acc[i][e] + bpr[e], 0.f);
      __hip_bfloat16 h, l;
      split_bf16(v, h, l);
      cfh[base + e] = h;
      cfl[base + e] = l;
    }
  }
}

// ---------------- feats = relu(concat(lf,rf) @ Wm + bm), bf16x3 MFMA ----------------
__global__ __launch_bounds__(256) void k_feats_mfma(
    const __hip_bfloat16* __restrict__ cfh, const __hip_bfloat16* __restrict__ cfl,
    const __hip_bfloat16* __restrict__ WmTh, const __hip_bfloat16* __restrict__ WmTl,
    const float* __restrict__ bm, float* __restrict__ feats, int ln, int n, int M) {
  __shared__ short Ash[2 * 128 * 40]; // [plane][m][k], padded stride 40
  __shared__ short Bsh[2 * 128 * 40]; // [plane][n][k]
  int tid = threadIdx.x;
  int Bn = cB * n;
  int rowTile = blockIdx.x * 128;
  int colTile = blockIdx.y * 128;
  int m0 = tid >> 2, kq8 = (tid & 3) * 8;

  long offA[2][2]; // [half][lf/rf]
  #pragma unroll
  for (int h = 0; h < 2; ++h) {
    int row = rowTile + m0 + h * 64;
    if (row >= M) row = M - 1;
    int dd = row / Bn;
    int r = row - dd * Bn;
    int b = r / n, i = r - b * n;
    offA[h][0] = ((long)((b * cL + i) * cL + dd)) * cSD;
    offA[h][1] = ((long)((b * cL + i + dd + 1) * cL + (ln - dd - 2))) * cSD;
  }
  long offB0 = (long)(colTile + m0) * 1024;
  long offB1 = (long)(colTile + m0 + 64) * 1024;

  f32x4 acc[4][4];
  f32x4 zero = {0.f, 0.f, 0.f, 0.f};
  #pragma unroll
  for (int a_ = 0; a_ < 4; ++a_)
    #pragma unroll
    for (int b_ = 0; b_ < 4; ++b_) acc[a_][b_] = zero;

  int lane = tid & 63, wid = tid >> 6;
  int wm = wid >> 1, wn = wid & 1;
  int fr = lane & 15, fq = lane >> 4;

  for (int kb = 0; kb < 1024; kb += 32) {
    int sideL = (kb < cSD) ? 0 : 1;
    int klocal = kb - sideL * cSD;
    int4 vA0h = *(const int4*)(const void*)(cfh + offA[0][sideL] + klocal + kq8);
    int4 vA1h = *(const int4*)(const void*)(cfh + offA[1][sideL] + klocal + kq8);
    int4 vA0l = *(const int4*)(const void*)(cfl + offA[0][sideL] + klocal + kq8);
    int4 vA1l = *(const int4*)(const void*)(cfl + offA[1][sideL] + klocal + kq8);
    int4 vB0h = *(const int4*)(const void*)(WmTh + offB0 + kb + kq8);
    int4 vB1h = *(const int4*)(const void*)(WmTh + offB1 + kb + kq8);
    int4 vB0l = *(const int4*)(const void*)(WmTl + offB0 + kb + kq8);
    int4 vB1l = *(const int4*)(const void*)(WmTl + offB1 + kb + kq8);
    __syncthreads();
    *(int4*)&Ash[(0 * 128 + m0) * 40 + kq8] = vA0h;
    *(int4*)&Ash[(0 * 128 + m0 + 64) * 40 + kq8] = vA1h;
    *(int4*)&Ash[(1 * 128 + m0) * 40 + kq8] = vA0l;
    *(int4*)&Ash[(1 * 128 + m0 + 64) * 40 + kq8] = vA1l;
    *(int4*)&Bsh[(0 * 128 + m0) * 40 + kq8] = vB0h;
    *(int4*)&Bsh[(0 * 128 + m0 + 64) * 40 + kq8] = vB1h;
    *(int4*)&Bsh[(1 * 128 + m0) * 40 + kq8] = vB0l;
    *(int4*)&Bsh[(1 * 128 + m0 + 64) * 40 + kq8] = vB1l;
    __syncthreads();
    short8 af[2][4], bf[2][4];
    #pragma unroll
    for (int pl = 0; pl < 2; ++pl)
      #pragma unroll
      for (int mf = 0; mf < 4; ++mf)
        af[pl][mf] = *(const short8*)&Ash[(pl * 128 + wm * 64 + mf * 16 + fr) * 40 + fq * 8];
    #pragma unroll
    for (int pl = 0; pl < 2; ++pl)
      #pragma unroll
      for (int nf = 0; nf < 4; ++nf)
        bf[pl][nf] = *(const short8*)&Bsh[(pl * 128 + wn * 64 + nf * 16 + fr) * 40 + fq * 8];
    #pragma unroll
    for (int mf = 0; mf < 4; ++mf)
      #pragma unroll
      for (int nf = 0; nf < 4; ++nf) {
        acc[mf][nf] = __builtin_amdgcn_mfma_f32_16x16x32_bf16(af[0][mf], bf[0][nf], acc[mf][nf], 0, 0, 0);
        acc[mf][nf] = __builtin_amdgcn_mfma_f32_16x16x32_bf16(af[0][mf], bf[1][nf], acc[mf][nf], 0, 0, 0);
        acc[mf][nf] = __builtin_amdgcn_mfma_f32_16x16x32_bf16(af[1][mf], bf[0][nf], acc[mf][nf], 0, 0, 0);
      }
  }
  #pragma unroll
  for (int mf = 0; mf < 4; ++mf)
    #pragma unroll
    for (int nf = 0; nf < 4; ++nf) {
      int col = colTile + wn * 64 + nf * 16 + fr;
      float bb = bm[col];
      #pragma unroll
      for (int r = 0; r < 4; ++r) {
        int row = rowTile + wm * 64 + mf * 16 + fq * 4 + r;
        feats[(size_t)row * cSD + col] = fmaxf(acc[mf][nf][r] + bb, 0.f);
      }
    }
}

// ---------------- outer-product accumulate + masses (cross-wave LDS reduce) ----------------
__global__ __launch_bounds__(256) void k_outer(const float* __restrict__ chart_p,
                                               const float* __restrict__ Gsum,
                                               float* __restrict__ O,
                                               float* __restrict__ masses,
                                               int ln, int n, int chunkStart) {
  __shared__ float lp[DMAX][cS];
  __shared__ float rp[DMAX][cS];
  __shared__ float mred[DMAX][4]; // per-wave mass partials
  int tid = threadIdx.x;
  int D = ln - 1;
  int Bn = cB * n;
  int row = chunkStart + blockIdx.x;
  int b = row / n, i = row - b * n;
  for (int dd = 0; dd < D; ++dd) {
    if (tid < 128)
      lp[dd][tid] = chart_p[(((size_t)(b * cL + i)) * cL + dd) * cS + tid];
    else
      rp[dd][tid - 128] =
          chart_p[(((size_t)(b * cL + i + dd + 1)) * cL + (ln - dd - 2)) * cS + (tid - 128)];
  }
  __syncthreads();
  float gs[64];
  #pragma unroll
  for (int j = 0; j < 64; ++j) gs[j] = Gsum[j * 256 + tid];
  float acc[64];
  #pragma unroll
  for (int j = 0; j < 64; ++j) acc[j] = 0.f;
  int s = tid >> 1, t0 = (tid & 1) << 6;
  for (int dd = 0; dd < D; ++dd) {
    float lps = lp[dd][s];
    float m = 0.f;
    #pragma unroll
    for (int qq = 0; qq < 16; ++qq) {
      float4 r4 = *(const float4*)&rp[dd][t0 + qq * 4];
      float rr[4] = {r4.x, r4.y, r4.z, r4.w};
      #pragma unroll
      for (int e = 0; e < 4; ++e) {
        float o = lps * rr[e];
        acc[qq * 4 + e] += o;
        m = fmaf(o, gs[qq * 4 + e], m);
      }
    }
    #pragma unroll
    for (int off = 32; off > 0; off >>= 1) m += __shfl_down(m, off, 64);
    if ((tid & 63) == 0) mred[dd][tid >> 6] = m; // each wave writes its own slot
  }
  __syncthreads();
  if (tid < D)
    masses[(size_t)tid * Bn + row] =
        mred[tid][0] + mred[tid][1] + mred[tid][2] + mred[tid][3];
  float* op = O + (size_t)blockIdx.x * cKP;
  #pragma unroll
  for (int j = 0; j < 64; ++j) op[j * 256 + tid] = acc[j];
}

// ---------------- scores GEMM: fp32 128x64 tile, kk=32, K-split 16 ----------------
__global__ __launch_bounds__(256) void k_scores(const float* __restrict__ O,
                                                const float* __restrict__ GpT,
                                                float* __restrict__ scoresP,
                                                int CHpad, int rows) {
  __shared__ float As[32][128]; // [k][m]
  __shared__ float Bs[32][64];  // [k][a]
  int tid = threadIdx.x;
  int rowTile = blockIdx.x * 128;
  int ks = blockIdx.y;          // 0..15
  int kstart = ks * (cKP / KS); // 1024 per split
  int sm = tid & 127, skq = (tid >> 7) * 16;      // A staging
  int bq = tid >> 4, bn4 = (tid & 15) * 4;        // B staging
  int m0 = (tid & 15) << 2, n0 = (tid >> 4) << 2; // micro tile
  const float* ap = O + (size_t)(rowTile + sm) * cKP + kstart + skq;
  float acc[8][4] = {};
  for (int kb = 0; kb < cKP / KS; kb += 32) {
    float4 a0 = *(const float4*)(ap + kb + 0);
    float4 a1 = *(const float4*)(ap + kb + 4);
    float4 a2 = *(const float4*)(ap + kb + 8);
    float4 a3 = *(const float4*)(ap + kb + 12);
    float4 b0 = *(const float4*)(GpT + (size_t)(kstart + kb + bq * 2) * cNT + bn4);
    float4 b1 = *(const float4*)(GpT + (size_t)(kstart + kb + bq * 2 + 1) * cNT + bn4);
    __syncthreads();
    As[skq + 0][sm] = a0.x; As[skq + 1][sm] = a0.y; As[skq + 2][sm] = a0.z; As[skq + 3][sm] = a0.w;
    As[skq + 4][sm] = a1.x; As[skq + 5][sm] = a1.y; As[skq + 6][sm] = a1.z; As[skq + 7][sm] = a1.w;
    As[skq + 8][sm] = a2.x; As[skq + 9][sm] = a2.y; As[skq + 10][sm] = a2.z; As[skq + 11][sm] = a2.w;
    As[skq + 12][sm] = a3.x; As[skq + 13][sm] = a3.y; As[skq + 14][sm] = a3.z; As[skq + 15][sm] = a3.w;
    *(float4*)&Bs[bq * 2][bn4] = b0;
    *(float4*)&Bs[bq * 2 + 1][bn4] = b1;
    __syncthreads();
    #pragma unroll
    for (int k = 0; k < 32; ++k) {
      float4 av0 = *(const float4*)&As[k][m0];
      float4 av1 = *(const float4*)&As[k][m0 + 64];
      float4 bv = *(const float4*)&Bs[k][n0];
      float ar[8] = {av0.x, av0.y, av0.z, av0.w, av1.x, av1.y, av1.z, av1.w};
      float br[4] = {bv.x, bv.y, bv.z, bv.w};
      #pragma unroll
      for (int i = 0; i < 8; ++i)
        #pragma unroll
        for (int j = 0; j < 4; ++j)
          acc[i][j] = fmaf(ar[i], br[j], acc[i][j]);
    }
  }
  #pragma unroll
  for (int i = 0; i < 8; ++i) {
    int row = rowTile + m0 + (i >> 2) * 64 + (i & 3);
    if (row < rows) {
      float4 o = {acc[i][0], acc[i][1], acc[i][2], acc[i][3]};
      *(float4*)&scoresP[((size_t)ks * CHpad + row) * cNT + n0] = o;
    }
  }
}

// ---------------- reduce K-split partials, normalize p, write chart_p ----------------
__global__ void k_normp(const float* __restrict__ scoresP,
                        float* __restrict__ chart_p, int ln, int nn, int CHpad,
                        int chunkStart) {
  int lr = blockIdx.x;
  int tid = threadIdx.x; // 64
  float v = 0.f;
  for (int ks = 0; ks < KS; ++ks)
    v += scoresP[((size_t)ks * CHpad + lr) * cNT + tid];
  float sum = v;
  #pragma unroll
  for (int off = 1; off < 64; off <<= 1) sum += __shfl_xor(sum, off, 64);
  int row = chunkStart + lr;
  int b = row / nn, i = row - b * nn;
  size_t base = (((size_t)(b * cL + i)) * cL + (ln - 1)) * cS;
  chart_p[base + tid] = v / (sum + cEPS);
  chart_p[base + 64 + tid] = 0.f;
}

// ---------------- combine feats with mass weights -> chart_f hi/lo ----------------
__global__ __launch_bounds__(256) void k_combine(const float* __restrict__ feats,
                                                 const float* __restrict__ masses,
                                                 __hip_bfloat16* __restrict__ cfh,
                                                 __hip_bfloat16* __restrict__ cfl,
                                                 int ln, int n) {
  __shared__ float lm[DMAX];
  int row = blockIdx.x, tid = threadIdx.x;
  int D = ln - 1, Bn = cB * n;
  int b = row / n, i = row - b * n;
  if (tid < D) lm[tid] = masses[(size_t)tid * Bn + row];
  __syncthreads();
  float msum = 0.f;
  for (int dd = 0; dd < D; ++dd) msum += lm[dd];
  float inv = 1.f / (msum + cEPS);
  size_t outbase = (((size_t)(b * cL + i)) * cL + (ln - 1)) * cSD;
  for (int h = tid; h < cSD; h += 256) {
    float acc = 0.f;
    for (int dd = 0; dd < D; ++dd)
      acc = fmaf(lm[dd], feats[((size_t)dd * Bn + row) * cSD + h], acc);
    float v = acc * inv;
    __hip_bfloat16 hh, ll;
    split_bf16(v, hh, ll);
    cfh[outbase + h] = hh;
    cfl[outbase + h] = ll;
  }
}

// ---------------- root ----------------
__global__ void k_root(const float* __restrict__ chart_p,
                       const __hip_bfloat16* __restrict__ cfh,
                       const __hip_bfloat16* __restrict__ cfl,
                       const float* __restrict__ starts,
                       float* __restrict__ out) {
  __shared__ float red[2];
  int b = blockIdx.x, tid = threadIdx.x; // 128
  float v = chart_p[(((size_t)(b * cL)) * cL + (cL - 1)) * cS + tid] * starts[tid];
  #pragma unroll
  for (int off = 1; off < 64; off <<= 1) v += __shfl_xor(v, off, 64);
  if ((tid & 63) == 0) red[tid >> 6] = v;
  __syncthreads();
  float score = red[0] + red[1];
  size_t fbase = (((size_t)(b * cL)) * cL + (cL - 1)) * cSD;
  for (int h = tid; h < cSD; h += 128) {
    float f = __bfloat162float(cfh[fbase + h]) + __bfloat162float(cfl[fbase + h]);
    out[(size_t)b * cSD + h] = f * score;
  }
}

extern "C" void kernel_launch(void* const* d_in, const int* in_sizes, int n_in,
                              void* d_out, int out_size, void* d_ws, size_t ws_size,
                              hipStream_t stream) {
  const int* word = (const int*)d_in[0];
  const float* WE = (const float*)d_in[1];
  const float* preterm = (const float*)d_in[2];
  const float* G = (const float*)d_in[3];
  const float* starts = (const float*)d_in[4];
  const float* Wp = (const float*)d_in[5];
  const float* bp = (const float*)d_in[6];
  const float* Wm = (const float*)d_in[7];
  const float* bm = (const float*)d_in[8];
  float* out = (float*)d_out;
  float* ws = (float*)d_ws;

  size_t off = 0;
  float* chart_p = ws + off; off += (size_t)cB * cL * cL * cS;
  __hip_bfloat16* cfh = (__hip_bfloat16*)(ws + off); off += (size_t)cB * cL * cL * cSD / 2;
  __hip_bfloat16* cfl = (__hip_bfloat16*)(ws + off); off += (size_t)cB * cL * cL * cSD / 2;
  float* GpT = ws + off; off += (size_t)cKP * cNT;
  float* Gsum = ws + off; off += cKP;
  __hip_bfloat16* WmTh = (__hip_bfloat16*)(ws + off); off += (size_t)cSD * 1024 / 2;
  __hip_bfloat16* WmTl = (__hip_bfloat16*)(ws + off); off += (size_t)cSD * 1024 / 2;
  float* feats = ws + off; off += (size_t)16448 * cSD;
  float* masses = ws + off; off += 16384;

  size_t avail = ws_size / sizeof(float) > off ? ws_size / sizeof(float) - off : 0;
  long perRow = cKP + KS * cNT;
  int CH = (int)(avail / perRow);
  if (CH > 1984) CH = 1984;
  CH &= ~127;
  if (CH < 128) CH = 128;
  int CHpad = CH;
  float* Obuf = ws + off; off += (size_t)CHpad * cKP;
  float* scoresP = ws + off; off += (size_t)CHpad * KS * cNT;

  k_prep_g<<<cKP / 256, 256, 0, stream>>>(G, GpT, Gsum);
  k_prep_wmt<<<(cSD * 1024) / 256, 256, 0, stream>>>(Wm, WmTh, WmTl);
  k_diag<<<cB * cL, 64, 0, stream>>>(word, preterm, chart_p);
  k_feat0<<<dim3((cB * cL) / 64, cSD / 64), 256, 0, stream>>>(word, WE, Wp, bp, cfh, cfl);

  for (int ln = 2; ln <= cL; ++ln) {
    int n = cL - ln + 1, D = ln - 1, Bn = cB * n;
    int M = D * Bn;
    int padM = (M + 127) & ~127;
    k_feats_mfma<<<dim3(padM / 128, cSD / 128), 256, 0, stream>>>(cfh, cfl, WmTh, WmTl, bm,
                                                                  feats, ln, n, M);
    for (int cs = 0; cs < Bn; cs += CH) {
      int rows = (Bn - cs) < CH ? (Bn - cs) : CH;
      int gx = (rows + 127) / 128;
      k_outer<<<rows, 256, 0, stream>>>(chart_p, Gsum, Obuf, masses, ln, n, cs);
      k_scores<<<dim3(gx, KS), 256, 0, stream>>>(Obuf, GpT, scoresP, CHpad, rows);
      k_normp<<<rows, 64, 0, stream>>>(scoresP, chart_p, ln, n, CHpad, cs);
    }
    k_combine<<<Bn, 256, 0, stream>>>(feats, masses, cfh, cfl, ln, n);
  }

  k_root<<<cB, 128, 0, stream>>>(chart_p, cfh, cfl, starts, out);
}

// Round 5
// 5198.787 us; speedup vs baseline: 3.1267x; 1.2316x over previous
//
#include <hip/hip_runtime.h>
#include <hip/hip_bf16.h>

// CYK forward. p-chain (scores/masses/chart_p) fp32 end-to-end; f-chain GEMM
// bf16x3 MFMA. Round 5: k_scores K-split 16->64 (occupancy 10%->~40%),
// k_feats_mfma register-prefetch pipeline (overlap global loads with MFMA).

typedef __attribute__((ext_vector_type(8))) short short8;  // 8 bf16 = 4 VGPR
typedef __attribute__((ext_vector_type(4))) float f32x4;

constexpr int cB = 64, cL = 32, cNT = 64, cS = 128, cV = 50000;
constexpr int cEMB = 512, cSD = 512, cKP = cS * cS; // 16384
constexpr int DMAX = 31, KS = 64;                   // k-slice = 256
constexpr float cEPS = 1e-9f;

__device__ __forceinline__ void split_bf16(float x, __hip_bfloat16& h, __hip_bfloat16& l) {
  h = __float2bfloat16(x);
  l = __float2bfloat16(x - __bfloat162float(h));
}

// ---------------- G permute + Gsum ----------------
__global__ __launch_bounds__(256) void k_prep_g(const float* __restrict__ G,
                                                float* __restrict__ GpT,
                                                float* __restrict__ Gsum) {
  int p = blockIdx.x * 256 + threadIdx.x;
  int q = p & 255, j = p >> 8;
  int s = q >> 1, t = ((q & 1) << 6) + j;
  int klog = s * cS + t;
  float accum = 0.f;
  for (int a = 0; a < cNT; ++a) {
    float g = G[(size_t)a * cKP + klog];
    GpT[(size_t)p * cNT + a] = g;
    accum += g;
  }
  Gsum[p] = accum;
}

// ---------------- WmT hi/lo split: WmT[n][k] = Wm[k][n] ----------------
__global__ __launch_bounds__(256) void k_prep_wmt(const float* __restrict__ Wm,
                                                  __hip_bfloat16* __restrict__ WmTh,
                                                  __hip_bfloat16* __restrict__ WmTl) {
  int idx = blockIdx.x * 256 + threadIdx.x; // n*1024 + k
  int k = idx & 1023, nn = idx >> 10;
  float v = Wm[(size_t)k * cSD + nn];
  __hip_bfloat16 h, l;
  split_bf16(v, h, l);
  WmTh[idx] = h;
  WmTl[idx] = l;
}

// ---------------- diagonal 0 of chart_p ----------------
__global__ void k_diag(const int* __restrict__ word,
                       const float* __restrict__ preterm,
                       float* __restrict__ chart_p) {
  int row = blockIdx.x; // b*L + l
  int t = threadIdx.x;  // 0..63
  int w = word[row];
  float v = preterm[(size_t)t * cV + w];
  float sum = v;
  #pragma unroll
  for (int off = 1; off < 64; off <<= 1) sum += __shfl_xor(sum, off, 64);
  size_t base = (size_t)row * cL * cS; // diag 0
  chart_p[base + t] = 0.f;
  chart_p[base + 64 + t] = v / (sum + cEPS);
}

// ---------------- fp32 GEMM micro (64x64 tile, 4x4/thread, kk=16) ----------------
__device__ __forceinline__ void micro16(const float (*As)[68], const float (*Bs)[68],
                                        int r0, int c0, float acc[4][4]) {
  #pragma unroll
  for (int k = 0; k < 16; ++k) {
    float4 a4 = *(const float4*)&As[k][r0];
    float4 b4 = *(const float4*)&Bs[k][c0];
    float ar[4] = {a4.x, a4.y, a4.z, a4.w};
    float br[4] = {b4.x, b4.y, b4.z, b4.w};
    #pragma unroll
    for (int i = 0; i < 4; ++i)
      #pragma unroll
      for (int j = 0; j < 4; ++j)
        acc[i][j] = fmaf(ar[i], br[j], acc[i][j]);
  }
}

// ---------------- feat0 = relu(gather(WE, word) @ Wp + bp) -> hi/lo planes ----------------
__global__ __launch_bounds__(256) void k_feat0(const int* __restrict__ word,
                                               const float* __restrict__ WE,
                                               const float* __restrict__ Wp,
                                               const float* __restrict__ bp,
                                               __hip_bfloat16* __restrict__ cfh,
                                               __hip_bfloat16* __restrict__ cfl) {
  __shared__ float As[16][68];
  __shared__ float Bs[16][68];
  int tid = threadIdx.x;
  int rowTile = blockIdx.x * 64;
  int n0 = blockIdx.y * 64;
  int lr = tid >> 2, lk = (tid & 3) << 2;
  int bk = tid >> 4, bn = (tid & 15) << 2;
  int r0 = (tid >> 4) << 2, c0 = (tid & 15) << 2;
  const float* ap = WE + (size_t)word[rowTile + lr] * cEMB;
  float acc[4][4] = {};
  for (int kb = 0; kb < cEMB; kb += 16) {
    float4 av = *(const float4*)(ap + kb + lk);
    float4 bv = *(const float4*)(Wp + (size_t)(kb + bk) * cSD + n0 + bn);
    __syncthreads();
    As[lk + 0][lr] = av.x; As[lk + 1][lr] = av.y;
    As[lk + 2][lr] = av.z; As[lk + 3][lr] = av.w;
    *(float4*)&Bs[bk][bn] = bv;
    __syncthreads();
    micro16(As, Bs, r0, c0, acc);
  }
  float4 bpv = *(const float4*)(bp + n0 + c0);
  float bpr[4] = {bpv.x, bpv.y, bpv.z, bpv.w};
  #pragma unroll
  for (int i = 0; i < 4; ++i) {
    int row = rowTile + r0 + i; // b*L + l; cell = row*cL + 0
    size_t base = ((size_t)row * cL) * cSD + n0 + c0;
    #pragma unroll
    for (int e = 0; e < 4; ++e) {
      float v = fmaxf(acc[i][e] + bpr[e], 0.f);
      __hip_bfloat16 h, l;
      split_bf16(v, h, l);
      cfh[base + e] = h;
      cfl[base + e] = l;
    }
  }
}

// ---------------- feats = relu(concat(lf,rf) @ Wm + bm), bf16x3 MFMA ----------------
// 128x128 tile, 4 waves of 64x64, 16x16x32 MFMA, K=1024, register prefetch.
__global__ __launch_bounds__(256) void k_feats_mfma(
    const __hip_bfloat16* __restrict__ cfh, const __hip_bfloat16* __restrict__ cfl,
    const __hip_bfloat16* __restrict__ WmTh, const __hip_bfloat16* __restrict__ WmTl,
    const float* __restrict__ bm, float* __restrict__ feats, int ln, int n, int M) {
  __shared__ short Ash[2 * 128 * 40]; // [plane][m][k], padded stride 40
  __shared__ short Bsh[2 * 128 * 40]; // [plane][n][k]
  int tid = threadIdx.x;
  int Bn = cB * n;
  int rowTile = blockIdx.x * 128;
  int colTile = blockIdx.y * 128;
  int m0 = tid >> 2, kq8 = (tid & 3) * 8;

  long offA[2][2]; // [half][lf/rf]
  #pragma unroll
  for (int h = 0; h < 2; ++h) {
    int row = rowTile + m0 + h * 64;
    if (row >= M) row = M - 1;
    int dd = row / Bn;
    int r = row - dd * Bn;
    int b = r / n, i = r - b * n;
    offA[h][0] = ((long)((b * cL + i) * cL + dd)) * cSD;
    offA[h][1] = ((long)((b * cL + i + dd + 1) * cL + (ln - dd - 2))) * cSD;
  }
  long offB0 = (long)(colTile + m0) * 1024;
  long offB1 = (long)(colTile + m0 + 64) * 1024;

  f32x4 acc[4][4];
  f32x4 zero = {0.f, 0.f, 0.f, 0.f};
  #pragma unroll
  for (int a_ = 0; a_ < 4; ++a_)
    #pragma unroll
    for (int b_ = 0; b_ < 4; ++b_) acc[a_][b_] = zero;

  int lane = tid & 63, wid = tid >> 6;
  int wm = wid >> 1, wn = wid & 1;
  int fr = lane & 15, fq = lane >> 4;

  // prologue: prefetch kb=0
  int4 pA0h = *(const int4*)(const void*)(cfh + offA[0][0] + kq8);
  int4 pA1h = *(const int4*)(const void*)(cfh + offA[1][0] + kq8);
  int4 pA0l = *(const int4*)(const void*)(cfl + offA[0][0] + kq8);
  int4 pA1l = *(const int4*)(const void*)(cfl + offA[1][0] + kq8);
  int4 pB0h = *(const int4*)(const void*)(WmTh + offB0 + kq8);
  int4 pB1h = *(const int4*)(const void*)(WmTh + offB1 + kq8);
  int4 pB0l = *(const int4*)(const void*)(WmTl + offB0 + kq8);
  int4 pB1l = *(const int4*)(const void*)(WmTl + offB1 + kq8);

  for (int kb = 0; kb < 1024; kb += 32) {
    __syncthreads();
    *(int4*)&Ash[(0 * 128 + m0) * 40 + kq8] = pA0h;
    *(int4*)&Ash[(0 * 128 + m0 + 64) * 40 + kq8] = pA1h;
    *(int4*)&Ash[(1 * 128 + m0) * 40 + kq8] = pA0l;
    *(int4*)&Ash[(1 * 128 + m0 + 64) * 40 + kq8] = pA1l;
    *(int4*)&Bsh[(0 * 128 + m0) * 40 + kq8] = pB0h;
    *(int4*)&Bsh[(0 * 128 + m0 + 64) * 40 + kq8] = pB1h;
    *(int4*)&Bsh[(1 * 128 + m0) * 40 + kq8] = pB0l;
    *(int4*)&Bsh[(1 * 128 + m0 + 64) * 40 + kq8] = pB1l;
    __syncthreads();
    int kn = kb + 32;
    if (kn < 1024) { // prefetch next k-chunk; overlaps the MFMA section below
      int sideL = (kn < cSD) ? 0 : 1;
      int klocal = kn - sideL * cSD;
      pA0h = *(const int4*)(const void*)(cfh + offA[0][sideL] + klocal + kq8);
      pA1h = *(const int4*)(const void*)(cfh + offA[1][sideL] + klocal + kq8);
      pA0l = *(const int4*)(const void*)(cfl + offA[0][sideL] + klocal + kq8);
      pA1l = *(const int4*)(const void*)(cfl + offA[1][sideL] + klocal + kq8);
      pB0h = *(const int4*)(const void*)(WmTh + offB0 + kn + kq8);
      pB1h = *(const int4*)(const void*)(WmTh + offB1 + kn + kq8);
      pB0l = *(const int4*)(const void*)(WmTl + offB0 + kn + kq8);
      pB1l = *(const int4*)(const void*)(WmTl + offB1 + kn + kq8);
    }
    short8 af[2][4], bf[2][4];
    #pragma unroll
    for (int pl = 0; pl < 2; ++pl)
      #pragma unroll
      for (int mf = 0; mf < 4; ++mf)
        af[pl][mf] = *(const short8*)&Ash[(pl * 128 + wm * 64 + mf * 16 + fr) * 40 + fq * 8];
    #pragma unroll
    for (int pl = 0; pl < 2; ++pl)
      #pragma unroll
      for (int nf = 0; nf < 4; ++nf)
        bf[pl][nf] = *(const short8*)&Bsh[(pl * 128 + wn * 64 + nf * 16 + fr) * 40 + fq * 8];
    #pragma unroll
    for (int mf = 0; mf < 4; ++mf)
      #pragma unroll
      for (int nf = 0; nf < 4; ++nf) {
        acc[mf][nf] = __builtin_amdgcn_mfma_f32_16x16x32_bf16(af[0][mf], bf[0][nf], acc[mf][nf], 0, 0, 0);
        acc[mf][nf] = __builtin_amdgcn_mfma_f32_16x16x32_bf16(af[0][mf], bf[1][nf], acc[mf][nf], 0, 0, 0);
        acc[mf][nf] = __builtin_amdgcn_mfma_f32_16x16x32_bf16(af[1][mf], bf[0][nf], acc[mf][nf], 0, 0, 0);
      }
  }
  #pragma unroll
  for (int mf = 0; mf < 4; ++mf)
    #pragma unroll
    for (int nf = 0; nf < 4; ++nf) {
      int col = colTile + wn * 64 + nf * 16 + fr;
      float bb = bm[col];
      #pragma unroll
      for (int r = 0; r < 4; ++r) {
        int row = rowTile + wm * 64 + mf * 16 + fq * 4 + r;
        feats[(size_t)row * cSD + col] = fmaxf(acc[mf][nf][r] + bb, 0.f);
      }
    }
}

// ---------------- outer-product accumulate + masses (cross-wave LDS reduce) ----------------
__global__ __launch_bounds__(256) void k_outer(const float* __restrict__ chart_p,
                                               const float* __restrict__ Gsum,
                                               float* __restrict__ O,
                                               float* __restrict__ masses,
                                               int ln, int n, int chunkStart) {
  __shared__ float lp[DMAX][cS];
  __shared__ float rp[DMAX][cS];
  __shared__ float mred[DMAX][4]; // per-wave mass partials
  int tid = threadIdx.x;
  int D = ln - 1;
  int Bn = cB * n;
  int row = chunkStart + blockIdx.x;
  int b = row / n, i = row - b * n;
  for (int dd = 0; dd < D; ++dd) {
    if (tid < 128)
      lp[dd][tid] = chart_p[(((size_t)(b * cL + i)) * cL + dd) * cS + tid];
    else
      rp[dd][tid - 128] =
          chart_p[(((size_t)(b * cL + i + dd + 1)) * cL + (ln - dd - 2)) * cS + (tid - 128)];
  }
  __syncthreads();
  float gs[64];
  #pragma unroll
  for (int j = 0; j < 64; ++j) gs[j] = Gsum[j * 256 + tid];
  float acc[64];
  #pragma unroll
  for (int j = 0; j < 64; ++j) acc[j] = 0.f;
  int s = tid >> 1, t0 = (tid & 1) << 6;
  for (int dd = 0; dd < D; ++dd) {
    float lps = lp[dd][s];
    float m = 0.f;
    #pragma unroll
    for (int qq = 0; qq < 16; ++qq) {
      float4 r4 = *(const float4*)&rp[dd][t0 + qq * 4];
      float rr[4] = {r4.x, r4.y, r4.z, r4.w};
      #pragma unroll
      for (int e = 0; e < 4; ++e) {
        float o = lps * rr[e];
        acc[qq * 4 + e] += o;
        m = fmaf(o, gs[qq * 4 + e], m);
      }
    }
    #pragma unroll
    for (int off = 32; off > 0; off >>= 1) m += __shfl_down(m, off, 64);
    if ((tid & 63) == 0) mred[dd][tid >> 6] = m; // each wave writes its own slot
  }
  __syncthreads();
  if (tid < D)
    masses[(size_t)tid * Bn + row] =
        mred[tid][0] + mred[tid][1] + mred[tid][2] + mred[tid][3];
  float* op = O + (size_t)blockIdx.x * cKP;
  #pragma unroll
  for (int j = 0; j < 64; ++j) op[j * 256 + tid] = acc[j];
}

// ---------------- scores GEMM: fp32 128x64 tile, kk=32, K-split 64 ----------------
__global__ __launch_bounds__(256) void k_scores(const float* __restrict__ O,
                                                const float* __restrict__ GpT,
                                                float* __restrict__ scoresP,
                                                int CHpad, int rows) {
  __shared__ float As[32][128]; // [k][m]
  __shared__ float Bs[32][64];  // [k][a]
  int tid = threadIdx.x;
  int rowTile = blockIdx.x * 128;
  int ks = blockIdx.y;          // 0..KS-1
  int kstart = ks * (cKP / KS); // 256 per split
  int sm = tid & 127, skq = (tid >> 7) * 16;      // A staging
  int bq = tid >> 4, bn4 = (tid & 15) * 4;        // B staging
  int m0 = (tid & 15) << 2, n0 = (tid >> 4) << 2; // micro tile
  const float* ap = O + (size_t)(rowTile + sm) * cKP + kstart + skq;
  float acc[8][4] = {};
  for (int kb = 0; kb < cKP / KS; kb += 32) {
    float4 a0 = *(const float4*)(ap + kb + 0);
    float4 a1 = *(const float4*)(ap + kb + 4);
    float4 a2 = *(const float4*)(ap + kb + 8);
    float4 a3 = *(const float4*)(ap + kb + 12);
    float4 b0 = *(const float4*)(GpT + (size_t)(kstart + kb + bq * 2) * cNT + bn4);
    float4 b1 = *(const float4*)(GpT + (size_t)(kstart + kb + bq * 2 + 1) * cNT + bn4);
    __syncthreads();
    As[skq + 0][sm] = a0.x; As[skq + 1][sm] = a0.y; As[skq + 2][sm] = a0.z; As[skq + 3][sm] = a0.w;
    As[skq + 4][sm] = a1.x; As[skq + 5][sm] = a1.y; As[skq + 6][sm] = a1.z; As[skq + 7][sm] = a1.w;
    As[skq + 8][sm] = a2.x; As[skq + 9][sm] = a2.y; As[skq + 10][sm] = a2.z; As[skq + 11][sm] = a2.w;
    As[skq + 12][sm] = a3.x; As[skq + 13][sm] = a3.y; As[skq + 14][sm] = a3.z; As[skq + 15][sm] = a3.w;
    *(float4*)&Bs[bq * 2][bn4] = b0;
    *(float4*)&Bs[bq * 2 + 1][bn4] = b1;
    __syncthreads();
    #pragma unroll
    for (int k = 0; k < 32; ++k) {
      float4 av0 = *(const float4*)&As[k][m0];
      float4 av1 = *(const float4*)&As[k][m0 + 64];
      float4 bv = *(const float4*)&Bs[k][n0];
      float ar[8] = {av0.x, av0.y, av0.z, av0.w, av1.x, av1.y, av1.z, av1.w};
      float br[4] = {bv.x, bv.y, bv.z, bv.w};
      #pragma unroll
      for (int i = 0; i < 8; ++i)
        #pragma unroll
        for (int j = 0; j < 4; ++j)
          acc[i][j] = fmaf(ar[i], br[j], acc[i][j]);
    }
  }
  #pragma unroll
  for (int i = 0; i < 8; ++i) {
    int row = rowTile + m0 + (i >> 2) * 64 + (i & 3);
    if (row < rows) {
      float4 o = {acc[i][0], acc[i][1], acc[i][2], acc[i][3]};
      *(float4*)&scoresP[((size_t)ks * CHpad + row) * cNT + n0] = o;
    }
  }
}

// ---------------- reduce K-split partials, normalize p, write chart_p ----------------
__global__ void k_normp(const float* __restrict__ scoresP,
                        float* __restrict__ chart_p, int ln, int nn, int CHpad,
                        int chunkStart) {
  int lr = blockIdx.x;
  int tid = threadIdx.x; // 64
  float v = 0.f;
  for (int ks = 0; ks < KS; ++ks)
    v += scoresP[((size_t)ks * CHpad + lr) * cNT + tid];
  float sum = v;
  #pragma unroll
  for (int off = 1; off < 64; off <<= 1) sum += __shfl_xor(sum, off, 64);
  int row = chunkStart + lr;
  int b = row / nn, i = row - b * nn;
  size_t base = (((size_t)(b * cL + i)) * cL + (ln - 1)) * cS;
  chart_p[base + tid] = v / (sum + cEPS);
  chart_p[base + 64 + tid] = 0.f;
}

// ---------------- combine feats with mass weights -> chart_f hi/lo ----------------
__global__ __launch_bounds__(256) void k_combine(const float* __restrict__ feats,
                                                 const float* __restrict__ masses,
                                                 __hip_bfloat16* __restrict__ cfh,
                                                 __hip_bfloat16* __restrict__ cfl,
                                                 int ln, int n) {
  __shared__ float lm[DMAX];
  int row = blockIdx.x, tid = threadIdx.x;
  int D = ln - 1, Bn = cB * n;
  int b = row / n, i = row - b * n;
  if (tid < D) lm[tid] = masses[(size_t)tid * Bn + row];
  __syncthreads();
  float msum = 0.f;
  for (int dd = 0; dd < D; ++dd) msum += lm[dd];
  float inv = 1.f / (msum + cEPS);
  size_t outbase = (((size_t)(b * cL + i)) * cL + (ln - 1)) * cSD;
  for (int h = tid; h < cSD; h += 256) {
    float acc = 0.f;
    for (int dd = 0; dd < D; ++dd)
      acc = fmaf(lm[dd], feats[((size_t)dd * Bn + row) * cSD + h], acc);
    float v = acc * inv;
    __hip_bfloat16 hh, ll;
    split_bf16(v, hh, ll);
    cfh[outbase + h] = hh;
    cfl[outbase + h] = ll;
  }
}

// ---------------- root ----------------
__global__ void k_root(const float* __restrict__ chart_p,
                       const __hip_bfloat16* __restrict__ cfh,
                       const __hip_bfloat16* __restrict__ cfl,
                       const float* __restrict__ starts,
                       float* __restrict__ out) {
  __shared__ float red[2];
  int b = blockIdx.x, tid = threadIdx.x; // 128
  float v = chart_p[(((size_t)(b * cL)) * cL + (cL - 1)) * cS + tid] * starts[tid];
  #pragma unroll
  for (int off = 1; off < 64; off <<= 1) v += __shfl_xor(v, off, 64);
  if ((tid & 63) == 0) red[tid >> 6] = v;
  __syncthreads();
  float score = red[0] + red[1];
  size_t fbase = (((size_t)(b * cL)) * cL + (cL - 1)) * cSD;
  for (int h = tid; h < cSD; h += 128) {
    float f = __bfloat162float(cfh[fbase + h]) + __bfloat162float(cfl[fbase + h]);
    out[(size_t)b * cSD + h] = f * score;
  }
}

extern "C" void kernel_launch(void* const* d_in, const int* in_sizes, int n_in,
                              void* d_out, int out_size, void* d_ws, size_t ws_size,
                              hipStream_t stream) {
  const int* word = (const int*)d_in[0];
  const float* WE = (const float*)d_in[1];
  const float* preterm = (const float*)d_in[2];
  const float* G = (const float*)d_in[3];
  const float* starts = (const float*)d_in[4];
  const float* Wp = (const float*)d_in[5];
  const float* bp = (const float*)d_in[6];
  const float* Wm = (const float*)d_in[7];
  const float* bm = (const float*)d_in[8];
  float* out = (float*)d_out;
  float* ws = (float*)d_ws;

  size_t off = 0;
  float* chart_p = ws + off; off += (size_t)cB * cL * cL * cS;
  __hip_bfloat16* cfh = (__hip_bfloat16*)(ws + off); off += (size_t)cB * cL * cL * cSD / 2;
  __hip_bfloat16* cfl = (__hip_bfloat16*)(ws + off); off += (size_t)cB * cL * cL * cSD / 2;
  float* GpT = ws + off; off += (size_t)cKP * cNT;
  float* Gsum = ws + off; off += cKP;
  __hip_bfloat16* WmTh = (__hip_bfloat16*)(ws + off); off += (size_t)cSD * 1024 / 2;
  __hip_bfloat16* WmTl = (__hip_bfloat16*)(ws + off); off += (size_t)cSD * 1024 / 2;
  float* feats = ws + off; off += (size_t)16448 * cSD;
  float* masses = ws + off; off += 16384;

  size_t avail = ws_size / sizeof(float) > off ? ws_size / sizeof(float) - off : 0;
  long perRow = cKP + KS * cNT; // 20480 floats/row
  int CH = (int)(avail / perRow);
  if (CH > 1984) CH = 1984;
  CH &= ~127;
  if (CH < 128) CH = 128;
  int CHpad = CH;
  float* Obuf = ws + off; off += (size_t)CHpad * cKP;
  float* scoresP = ws + off; off += (size_t)CHpad * KS * cNT;

  k_prep_g<<<cKP / 256, 256, 0, stream>>>(G, GpT, Gsum);
  k_prep_wmt<<<(cSD * 1024) / 256, 256, 0, stream>>>(Wm, WmTh, WmTl);
  k_diag<<<cB * cL, 64, 0, stream>>>(word, preterm, chart_p);
  k_feat0<<<dim3((cB * cL) / 64, cSD / 64), 256, 0, stream>>>(word, WE, Wp, bp, cfh, cfl);

  for (int ln = 2; ln <= cL; ++ln) {
    int n = cL - ln + 1, D = ln - 1, Bn = cB * n;
    int M = D * Bn;
    int padM = (M + 127) & ~127;
    k_feats_mfma<<<dim3(padM / 128, cSD / 128), 256, 0, stream>>>(cfh, cfl, WmTh, WmTl, bm,
                                                                  feats, ln, n, M);
    for (int cs = 0; cs < Bn; cs += CH) {
      int rows = (Bn - cs) < CH ? (Bn - cs) : CH;
      int gx = (rows + 127) / 128;
      k_outer<<<rows, 256, 0, stream>>>(chart_p, Gsum, Obuf, masses, ln, n, cs);
      k_scores<<<dim3(gx, KS), 256, 0, stream>>>(Obuf, GpT, scoresP, CHpad, rows);
      k_normp<<<rows, 64, 0, stream>>>(scoresP, chart_p, ln, n, CHpad, cs);
    }
    k_combine<<<Bn, 256, 0, stream>>>(feats, masses, cfh, cfl, ln, n);
  }

  k_root<<<cB, 128, 0, stream>>>(chart_p, cfh, cfl, starts, out);
}

// Round 6
// 4605.246 us; speedup vs baseline: 3.5297x; 1.1289x over previous
//
#include <hip/hip_runtime.h>
#include <hip/hip_bf16.h>

// CYK forward. p-chain fp32 end-to-end; f-chain GEMM bf16x3 MFMA.
// Round 6: k_outer slimmed (no mass work, ~84 VGPR, float4 staging+stores,
// thread-contiguous O layout); mass via chart_v = Gsum2^T.p precomputed at
// cell creation (k_diag/k_normp), dotted with lp inside k_combine.

typedef __attribute__((ext_vector_type(8))) short short8;  // 8 bf16 = 4 VGPR
typedef __attribute__((ext_vector_type(4))) float f32x4;

constexpr int cB = 64, cL = 32, cNT = 64, cS = 128, cV = 50000;
constexpr int cEMB = 512, cSD = 512, cKP = cS * cS; // 16384
constexpr int DMAX = 31, KS = 64;                   // k-slice = 256
constexpr float cEPS = 1e-9f;

__device__ __forceinline__ void split_bf16(float x, __hip_bfloat16& h, __hip_bfloat16& l) {
  h = __float2bfloat16(x);
  l = __float2bfloat16(x - __bfloat162float(h));
}

// ---------------- G permute (thread-contiguous k-order) + GsumT ----------------
// p = q*64 + j  <->  s = q>>1, t = ((q&1)<<6)|j   (q = owning thread in k_outer)
__global__ __launch_bounds__(256) void k_prep_g(const float* __restrict__ G,
                                                float* __restrict__ GpT,
                                                float* __restrict__ GsumT) {
  int p = blockIdx.x * 256 + threadIdx.x;
  int q = p >> 6, j = p & 63;
  int s = q >> 1, t = ((q & 1) << 6) | j;
  int klog = s * cS + t;
  float accum = 0.f;
  for (int a = 0; a < cNT; ++a) {
    float g = G[(size_t)a * cKP + klog];
    GpT[(size_t)p * cNT + a] = g;
    accum += g;
  }
  GsumT[t * cS + s] = accum; // transposed standard layout for coalesced v-compute
}

// ---------------- WmT hi/lo split: WmT[n][k] = Wm[k][n] ----------------
__global__ __launch_bounds__(256) void k_prep_wmt(const float* __restrict__ Wm,
                                                  __hip_bfloat16* __restrict__ WmTh,
                                                  __hip_bfloat16* __restrict__ WmTl) {
  int idx = blockIdx.x * 256 + threadIdx.x; // n*1024 + k
  int k = idx & 1023, nn = idx >> 10;
  float v = Wm[(size_t)k * cSD + nn];
  __hip_bfloat16 h, l;
  split_bf16(v, h, l);
  WmTh[idx] = h;
  WmTl[idx] = l;
}

// ---------------- diagonal 0 of chart_p + chart_v ----------------
__global__ void k_diag(const int* __restrict__ word,
                       const float* __restrict__ preterm,
                       const float* __restrict__ GsumT,
                       float* __restrict__ chart_p,
                       float* __restrict__ chart_v) {
  __shared__ float ps[128];
  int row = blockIdx.x; // b*L + l
  int tid = threadIdx.x; // 0..127
  int w = word[row];
  float val = (tid >= 64) ? preterm[(size_t)(tid - 64) * cV + w] : 0.f;
  float sum = val;
  #pragma unroll
  for (int off = 1; off < 64; off <<= 1) sum += __shfl_xor(sum, off, 64);
  float p_ = (tid >= 64) ? val / (sum + cEPS) : 0.f;
  size_t base = (size_t)row * cL * cS; // diag 0
  chart_p[base + tid] = p_;
  ps[tid] = p_;
  __syncthreads();
  float v = 0.f;
  for (int t = 64; t < 128; ++t) v = fmaf(GsumT[t * cS + tid], ps[t], v);
  chart_v[base + tid] = v;
}

// ---------------- fp32 GEMM micro (64x64 tile, 4x4/thread, kk=16) ----------------
__device__ __forceinline__ void micro16(const float (*As)[68], const float (*Bs)[68],
                                        int r0, int c0, float acc[4][4]) {
  #pragma unroll
  for (int k = 0; k < 16; ++k) {
    float4 a4 = *(const float4*)&As[k][r0];
    float4 b4 = *(const float4*)&Bs[k][c0];
    float ar[4] = {a4.x, a4.y, a4.z, a4.w};
    float br[4] = {b4.x, b4.y, b4.z, b4.w};
    #pragma unroll
    for (int i = 0; i < 4; ++i)
      #pragma unroll
      for (int j = 0; j < 4; ++j)
        acc[i][j] = fmaf(ar[i], br[j], acc[i][j]);
  }
}

// ---------------- feat0 = relu(gather(WE, word) @ Wp + bp) -> hi/lo planes ----------------
__global__ __launch_bounds__(256) void k_feat0(const int* __restrict__ word,
                                               const float* __restrict__ WE,
                                               const float* __restrict__ Wp,
                                               const float* __restrict__ bp,
                                               __hip_bfloat16* __restrict__ cfh,
                                               __hip_bfloat16* __restrict__ cfl) {
  __shared__ float As[16][68];
  __shared__ float Bs[16][68];
  int tid = threadIdx.x;
  int rowTile = blockIdx.x * 64;
  int n0 = blockIdx.y * 64;
  int lr = tid >> 2, lk = (tid & 3) << 2;
  int bk = tid >> 4, bn = (tid & 15) << 2;
  int r0 = (tid >> 4) << 2, c0 = (tid & 15) << 2;
  const float* ap = WE + (size_t)word[rowTile + lr] * cEMB;
  float acc[4][4] = {};
  for (int kb = 0; kb < cEMB; kb += 16) {
    float4 av = *(const float4*)(ap + kb + lk);
    float4 bv = *(const float4*)(Wp + (size_t)(kb + bk) * cSD + n0 + bn);
    __syncthreads();
    As[lk + 0][lr] = av.x; As[lk + 1][lr] = av.y;
    As[lk + 2][lr] = av.z; As[lk + 3][lr] = av.w;
    *(float4*)&Bs[bk][bn] = bv;
    __syncthreads();
    micro16(As, Bs, r0, c0, acc);
  }
  float4 bpv = *(const float4*)(bp + n0 + c0);
  float bpr[4] = {bpv.x, bpv.y, bpv.z, bpv.w};
  #pragma unroll
  for (int i = 0; i < 4; ++i) {
    int row = rowTile + r0 + i; // b*L + l; cell = row*cL + 0
    size_t base = ((size_t)row * cL) * cSD + n0 + c0;
    #pragma unroll
    for (int e = 0; e < 4; ++e) {
      float v = fmaxf(acc[i][e] + bpr[e], 0.f);
      __hip_bfloat16 h, l;
      split_bf16(v, h, l);
      cfh[base + e] = h;
      cfl[base + e] = l;
    }
  }
}

// ---------------- feats = relu(concat(lf,rf) @ Wm + bm), bf16x3 MFMA ----------------
__global__ __launch_bounds__(256) void k_feats_mfma(
    const __hip_bfloat16* __restrict__ cfh, const __hip_bfloat16* __restrict__ cfl,
    const __hip_bfloat16* __restrict__ WmTh, const __hip_bfloat16* __restrict__ WmTl,
    const float* __restrict__ bm, float* __restrict__ feats, int ln, int n, int M) {
  __shared__ short Ash[2 * 128 * 40]; // [plane][m][k], padded stride 40
  __shared__ short Bsh[2 * 128 * 40]; // [plane][n][k]
  int tid = threadIdx.x;
  int Bn = cB * n;
  int rowTile = blockIdx.x * 128;
  int colTile = blockIdx.y * 128;
  int m0 = tid >> 2, kq8 = (tid & 3) * 8;

  long offA[2][2]; // [half][lf/rf]
  #pragma unroll
  for (int h = 0; h < 2; ++h) {
    int row = rowTile + m0 + h * 64;
    if (row >= M) row = M - 1;
    int dd = row / Bn;
    int r = row - dd * Bn;
    int b = r / n, i = r - b * n;
    offA[h][0] = ((long)((b * cL + i) * cL + dd)) * cSD;
    offA[h][1] = ((long)((b * cL + i + dd + 1) * cL + (ln - dd - 2))) * cSD;
  }
  long offB0 = (long)(colTile + m0) * 1024;
  long offB1 = (long)(colTile + m0 + 64) * 1024;

  f32x4 acc[4][4];
  f32x4 zero = {0.f, 0.f, 0.f, 0.f};
  #pragma unroll
  for (int a_ = 0; a_ < 4; ++a_)
    #pragma unroll
    for (int b_ = 0; b_ < 4; ++b_) acc[a_][b_] = zero;

  int lane = tid & 63, wid = tid >> 6;
  int wm = wid >> 1, wn = wid & 1;
  int fr = lane & 15, fq = lane >> 4;

  // prologue: prefetch kb=0
  int4 pA0h = *(const int4*)(const void*)(cfh + offA[0][0] + kq8);
  int4 pA1h = *(const int4*)(const void*)(cfh + offA[1][0] + kq8);
  int4 pA0l = *(const int4*)(const void*)(cfl + offA[0][0] + kq8);
  int4 pA1l = *(const int4*)(const void*)(cfl + offA[1][0] + kq8);
  int4 pB0h = *(const int4*)(const void*)(WmTh + offB0 + kq8);
  int4 pB1h = *(const int4*)(const void*)(WmTh + offB1 + kq8);
  int4 pB0l = *(const int4*)(const void*)(WmTl + offB0 + kq8);
  int4 pB1l = *(const int4*)(const void*)(WmTl + offB1 + kq8);

  for (int kb = 0; kb < 1024; kb += 32) {
    __syncthreads();
    *(int4*)&Ash[(0 * 128 + m0) * 40 + kq8] = pA0h;
    *(int4*)&Ash[(0 * 128 + m0 + 64) * 40 + kq8] = pA1h;
    *(int4*)&Ash[(1 * 128 + m0) * 40 + kq8] = pA0l;
    *(int4*)&Ash[(1 * 128 + m0 + 64) * 40 + kq8] = pA1l;
    *(int4*)&Bsh[(0 * 128 + m0) * 40 + kq8] = pB0h;
    *(int4*)&Bsh[(0 * 128 + m0 + 64) * 40 + kq8] = pB1h;
    *(int4*)&Bsh[(1 * 128 + m0) * 40 + kq8] = pB0l;
    *(int4*)&Bsh[(1 * 128 + m0 + 64) * 40 + kq8] = pB1l;
    __syncthreads();
    int kn = kb + 32;
    if (kn < 1024) {
      int sideL = (kn < cSD) ? 0 : 1;
      int klocal = kn - sideL * cSD;
      pA0h = *(const int4*)(const void*)(cfh + offA[0][sideL] + klocal + kq8);
      pA1h = *(const int4*)(const void*)(cfh + offA[1][sideL] + klocal + kq8);
      pA0l = *(const int4*)(const void*)(cfl + offA[0][sideL] + klocal + kq8);
      pA1l = *(const int4*)(const void*)(cfl + offA[1][sideL] + klocal + kq8);
      pB0h = *(const int4*)(const void*)(WmTh + offB0 + kn + kq8);
      pB1h = *(const int4*)(const void*)(WmTh + offB1 + kn + kq8);
      pB0l = *(const int4*)(const void*)(WmTl + offB0 + kn + kq8);
      pB1l = *(const int4*)(const void*)(WmTl + offB1 + kn + kq8);
    }
    short8 af[2][4], bf[2][4];
    #pragma unroll
    for (int pl = 0; pl < 2; ++pl)
      #pragma unroll
      for (int mf = 0; mf < 4; ++mf)
        af[pl][mf] = *(const short8*)&Ash[(pl * 128 + wm * 64 + mf * 16 + fr) * 40 + fq * 8];
    #pragma unroll
    for (int pl = 0; pl < 2; ++pl)
      #pragma unroll
      for (int nf = 0; nf < 4; ++nf)
        bf[pl][nf] = *(const short8*)&Bsh[(pl * 128 + wn * 64 + nf * 16 + fr) * 40 + fq * 8];
    #pragma unroll
    for (int mf = 0; mf < 4; ++mf)
      #pragma unroll
      for (int nf = 0; nf < 4; ++nf) {
        acc[mf][nf] = __builtin_amdgcn_mfma_f32_16x16x32_bf16(af[0][mf], bf[0][nf], acc[mf][nf], 0, 0, 0);
        acc[mf][nf] = __builtin_amdgcn_mfma_f32_16x16x32_bf16(af[0][mf], bf[1][nf], acc[mf][nf], 0, 0, 0);
        acc[mf][nf] = __builtin_amdgcn_mfma_f32_16x16x32_bf16(af[1][mf], bf[0][nf], acc[mf][nf], 0, 0, 0);
      }
  }
  #pragma unroll
  for (int mf = 0; mf < 4; ++mf)
    #pragma unroll
    for (int nf = 0; nf < 4; ++nf) {
      int col = colTile + wn * 64 + nf * 16 + fr;
      float bb = bm[col];
      #pragma unroll
      for (int r = 0; r < 4; ++r) {
        int row = rowTile + wm * 64 + mf * 16 + fq * 4 + r;
        feats[(size_t)row * cSD + col] = fmaxf(acc[mf][nf][r] + bb, 0.f);
      }
    }
}

// ---------------- outer-product accumulate (slim: no mass) ----------------
__global__ __launch_bounds__(256) void k_outer(const float* __restrict__ chart_p,
                                               float* __restrict__ O,
                                               int ln, int n, int chunkStart) {
  __shared__ float lp[DMAX][cS];
  __shared__ float rp[DMAX][cS];
  int tid = threadIdx.x;
  int D = ln - 1;
  int row = chunkStart + blockIdx.x;
  int b = row / n, i = row - b * n;
  // float4 staging: threads 0..127 -> lp, 128..255 -> rp
  if (tid < 128) {
    int lane32 = tid & 31;
    for (int dd = tid >> 5; dd < D; dd += 4) {
      const float* src = chart_p + (((size_t)(b * cL + i)) * cL + dd) * cS + lane32 * 4;
      *(float4*)&lp[dd][lane32 * 4] = *(const float4*)src;
    }
  } else {
    int t2 = tid - 128;
    int lane32 = t2 & 31;
    for (int dd = t2 >> 5; dd < D; dd += 4) {
      const float* src =
          chart_p + (((size_t)(b * cL + i + dd + 1)) * cL + (ln - dd - 2)) * cS + lane32 * 4;
      *(float4*)&rp[dd][lane32 * 4] = *(const float4*)src;
    }
  }
  __syncthreads();
  float acc[64];
  #pragma unroll
  for (int j = 0; j < 64; ++j) acc[j] = 0.f;
  int s = tid >> 1, t0 = (tid & 1) << 6;
  for (int dd = 0; dd < D; ++dd) {
    float lps = lp[dd][s];
    #pragma unroll
    for (int qq = 0; qq < 16; ++qq) {
      float4 r4 = *(const float4*)&rp[dd][t0 + qq * 4];
      acc[qq * 4 + 0] = fmaf(lps, r4.x, acc[qq * 4 + 0]);
      acc[qq * 4 + 1] = fmaf(lps, r4.y, acc[qq * 4 + 1]);
      acc[qq * 4 + 2] = fmaf(lps, r4.z, acc[qq * 4 + 2]);
      acc[qq * 4 + 3] = fmaf(lps, r4.w, acc[qq * 4 + 3]);
    }
  }
  // thread-contiguous store: p = tid*64 + j  (matches k_prep_g decode)
  float* op = O + (size_t)blockIdx.x * cKP + (size_t)tid * 64;
  #pragma unroll
  for (int j = 0; j < 16; ++j) {
    float4 o = {acc[j * 4 + 0], acc[j * 4 + 1], acc[j * 4 + 2], acc[j * 4 + 3]};
    *(float4*)&op[j * 4] = o;
  }
}

// ---------------- scores GEMM: fp32 128x64 tile, kk=32, K-split 64 ----------------
__global__ __launch_bounds__(256) void k_scores(const float* __restrict__ O,
                                                const float* __restrict__ GpT,
                                                float* __restrict__ scoresP,
                                                int CHpad, int rows) {
  __shared__ float As[32][128]; // [k][m]
  __shared__ float Bs[32][64];  // [k][a]
  int tid = threadIdx.x;
  int rowTile = blockIdx.x * 128;
  int ks = blockIdx.y;          // 0..KS-1
  int kstart = ks * (cKP / KS); // 256 per split
  int sm = tid & 127, skq = (tid >> 7) * 16;      // A staging
  int bq = tid >> 4, bn4 = (tid & 15) * 4;        // B staging
  int m0 = (tid & 15) << 2, n0 = (tid >> 4) << 2; // micro tile
  const float* ap = O + (size_t)(rowTile + sm) * cKP + kstart + skq;
  float acc[8][4] = {};
  for (int kb = 0; kb < cKP / KS; kb += 32) {
    float4 a0 = *(const float4*)(ap + kb + 0);
    float4 a1 = *(const float4*)(ap + kb + 4);
    float4 a2 = *(const float4*)(ap + kb + 8);
    float4 a3 = *(const float4*)(ap + kb + 12);
    float4 b0 = *(const float4*)(GpT + (size_t)(kstart + kb + bq * 2) * cNT + bn4);
    float4 b1 = *(const float4*)(GpT + (size_t)(kstart + kb + bq * 2 + 1) * cNT + bn4);
    __syncthreads();
    As[skq + 0][sm] = a0.x; As[skq + 1][sm] = a0.y; As[skq + 2][sm] = a0.z; As[skq + 3][sm] = a0.w;
    As[skq + 4][sm] = a1.x; As[skq + 5][sm] = a1.y; As[skq + 6][sm] = a1.z; As[skq + 7][sm] = a1.w;
    As[skq + 8][sm] = a2.x; As[skq + 9][sm] = a2.y; As[skq + 10][sm] = a2.z; As[skq + 11][sm] = a2.w;
    As[skq + 12][sm] = a3.x; As[skq + 13][sm] = a3.y; As[skq + 14][sm] = a3.z; As[skq + 15][sm] = a3.w;
    *(float4*)&Bs[bq * 2][bn4] = b0;
    *(float4*)&Bs[bq * 2 + 1][bn4] = b1;
    __syncthreads();
    #pragma unroll
    for (int k = 0; k < 32; ++k) {
      float4 av0 = *(const float4*)&As[k][m0];
      float4 av1 = *(const float4*)&As[k][m0 + 64];
      float4 bv = *(const float4*)&Bs[k][n0];
      float ar[8] = {av0.x, av0.y, av0.z, av0.w, av1.x, av1.y, av1.z, av1.w};
      float br[4] = {bv.x, bv.y, bv.z, bv.w};
      #pragma unroll
      for (int i = 0; i < 8; ++i)
        #pragma unroll
        for (int j = 0; j < 4; ++j)
          acc[i][j] = fmaf(ar[i], br[j], acc[i][j]);
    }
  }
  #pragma unroll
  for (int i = 0; i < 8; ++i) {
    int row = rowTile + m0 + (i >> 2) * 64 + (i & 3);
    if (row < rows) {
      float4 o = {acc[i][0], acc[i][1], acc[i][2], acc[i][3]};
      *(float4*)&scoresP[((size_t)ks * CHpad + row) * cNT + n0] = o;
    }
  }
}

// ---------------- reduce K-split partials, normalize p, write chart_p + chart_v ----------------
__global__ void k_normp(const float* __restrict__ scoresP,
                        const float* __restrict__ GsumT,
                        float* __restrict__ chart_p,
                        float* __restrict__ chart_v,
                        int ln, int nn, int CHpad, int chunkStart) {
  __shared__ float ps[64];
  int lr = blockIdx.x;
  int tid = threadIdx.x; // 0..127
  float val = 0.f;
  if (tid < 64) {
    for (int ks = 0; ks < KS; ++ks)
      val += scoresP[((size_t)ks * CHpad + lr) * cNT + tid];
  }
  float sum = val;
  #pragma unroll
  for (int off = 1; off < 64; off <<= 1) sum += __shfl_xor(sum, off, 64);
  float p_ = (tid < 64) ? val / (sum + cEPS) : 0.f;
  int row = chunkStart + lr;
  int b = row / nn, i = row - b * nn;
  size_t base = (((size_t)(b * cL + i)) * cL + (ln - 1)) * cS;
  chart_p[base + tid] = p_;
  if (tid < 64) ps[tid] = p_;
  __syncthreads();
  float v = 0.f;
  for (int t = 0; t < 64; ++t) v = fmaf(GsumT[t * cS + tid], ps[t], v);
  chart_v[base + tid] = v;
}

// ---------------- combine: masses via lp.v dots, weighted feats -> chart_f hi/lo ----------------
__global__ __launch_bounds__(256) void k_combine(const float* __restrict__ feats,
                                                 const float* __restrict__ chart_p,
                                                 const float* __restrict__ chart_v,
                                                 __hip_bfloat16* __restrict__ cfh,
                                                 __hip_bfloat16* __restrict__ cfl,
                                                 int ln, int n) {
  __shared__ float lm[DMAX];
  __shared__ float red4[2][2];
  int row = blockIdx.x, tid = threadIdx.x;
  int D = ln - 1, Bn = cB * n;
  int b = row / n, i = row - b * n;
  int half = tid >> 7, l = tid & 127;
  for (int base0 = 0; base0 < D; base0 += 2) {
    int dd = base0 + half;
    float part = 0.f;
    if (dd < D) {
      size_t lpc = (((size_t)(b * cL + i)) * cL + dd) * cS;
      size_t vpc = (((size_t)(b * cL + i + dd + 1)) * cL + (ln - dd - 2)) * cS;
      part = chart_p[lpc + l] * chart_v[vpc + l];
    }
    #pragma unroll
    for (int off = 1; off < 64; off <<= 1) part += __shfl_xor(part, off, 64);
    if ((tid & 63) == 0) red4[half][(tid >> 6) & 1] = part;
    __syncthreads();
    if (tid < 2 && base0 + tid < D) lm[base0 + tid] = red4[tid][0] + red4[tid][1];
    __syncthreads();
  }
  float msum = 0.f;
  for (int dd = 0; dd < D; ++dd) msum += lm[dd];
  float inv = 1.f / (msum + cEPS);
  size_t outbase = (((size_t)(b * cL + i)) * cL + (ln - 1)) * cSD;
  for (int h = tid; h < cSD; h += 256) {
    float acc = 0.f;
    for (int dd = 0; dd < D; ++dd)
      acc = fmaf(lm[dd], feats[((size_t)dd * Bn + row) * cSD + h], acc);
    float v = acc * inv;
    __hip_bfloat16 hh, ll;
    split_bf16(v, hh, ll);
    cfh[outbase + h] = hh;
    cfl[outbase + h] = ll;
  }
}

// ---------------- root ----------------
__global__ void k_root(const float* __restrict__ chart_p,
                       const __hip_bfloat16* __restrict__ cfh,
                       const __hip_bfloat16* __restrict__ cfl,
                       const float* __restrict__ starts,
                       float* __restrict__ out) {
  __shared__ float red[2];
  int b = blockIdx.x, tid = threadIdx.x; // 128
  float v = chart_p[(((size_t)(b * cL)) * cL + (cL - 1)) * cS + tid] * starts[tid];
  #pragma unroll
  for (int off = 1; off < 64; off <<= 1) v += __shfl_xor(v, off, 64);
  if ((tid & 63) == 0) red[tid >> 6] = v;
  __syncthreads();
  float score = red[0] + red[1];
  size_t fbase = (((size_t)(b * cL)) * cL + (cL - 1)) * cSD;
  for (int h = tid; h < cSD; h += 128) {
    float f = __bfloat162float(cfh[fbase + h]) + __bfloat162float(cfl[fbase + h]);
    out[(size_t)b * cSD + h] = f * score;
  }
}

extern "C" void kernel_launch(void* const* d_in, const int* in_sizes, int n_in,
                              void* d_out, int out_size, void* d_ws, size_t ws_size,
                              hipStream_t stream) {
  const int* word = (const int*)d_in[0];
  const float* WE = (const float*)d_in[1];
  const float* preterm = (const float*)d_in[2];
  const float* G = (const float*)d_in[3];
  const float* starts = (const float*)d_in[4];
  const float* Wp = (const float*)d_in[5];
  const float* bp = (const float*)d_in[6];
  const float* Wm = (const float*)d_in[7];
  const float* bm = (const float*)d_in[8];
  float* out = (float*)d_out;
  float* ws = (float*)d_ws;

  size_t off = 0;
  float* chart_p = ws + off; off += (size_t)cB * cL * cL * cS;  // 33.5 MB
  float* chart_v = ws + off; off += (size_t)cB * cL * cL * cS;  // 33.5 MB
  __hip_bfloat16* cfh = (__hip_bfloat16*)(ws + off); off += (size_t)cB * cL * cL * cSD / 2;
  __hip_bfloat16* cfl = (__hip_bfloat16*)(ws + off); off += (size_t)cB * cL * cL * cSD / 2;
  float* GpT = ws + off; off += (size_t)cKP * cNT;
  float* GsumT = ws + off; off += cKP;
  __hip_bfloat16* WmTh = (__hip_bfloat16*)(ws + off); off += (size_t)cSD * 1024 / 2;
  __hip_bfloat16* WmTl = (__hip_bfloat16*)(ws + off); off += (size_t)cSD * 1024 / 2;
  float* feats = ws + off; off += (size_t)16448 * cSD;

  size_t avail = ws_size / sizeof(float) > off ? ws_size / sizeof(float) - off : 0;
  long perRow = cKP + KS * cNT; // 20480 floats/row
  int CH = (int)(avail / perRow);
  if (CH > 1984) CH = 1984;
  CH &= ~127;
  if (CH < 128) CH = 128;
  int CHpad = CH;
  float* Obuf = ws + off; off += (size_t)CHpad * cKP;
  float* scoresP = ws + off; off += (size_t)CHpad * KS * cNT;

  k_prep_g<<<cKP / 256, 256, 0, stream>>>(G, GpT, GsumT);
  k_prep_wmt<<<(cSD * 1024) / 256, 256, 0, stream>>>(Wm, WmTh, WmTl);
  k_diag<<<cB * cL, 128, 0, stream>>>(word, preterm, GsumT, chart_p, chart_v);
  k_feat0<<<dim3((cB * cL) / 64, cSD / 64), 256, 0, stream>>>(word, WE, Wp, bp, cfh, cfl);

  for (int ln = 2; ln <= cL; ++ln) {
    int n = cL - ln + 1, D = ln - 1, Bn = cB * n;
    int M = D * Bn;
    int padM = (M + 127) & ~127;
    k_feats_mfma<<<dim3(padM / 128, cSD / 128), 256, 0, stream>>>(cfh, cfl, WmTh, WmTl, bm,
                                                                  feats, ln, n, M);
    for (int cs = 0; cs < Bn; cs += CH) {
      int rows = (Bn - cs) < CH ? (Bn - cs) : CH;
      int gx = (rows + 127) / 128;
      k_outer<<<rows, 256, 0, stream>>>(chart_p, Obuf, ln, n, cs);
      k_scores<<<dim3(gx, KS), 256, 0, stream>>>(Obuf, GpT, scoresP, CHpad, rows);
      k_normp<<<rows, 128, 0, stream>>>(scoresP, GsumT, chart_p, chart_v, ln, n, CHpad, cs);
    }
    k_combine<<<Bn, 256, 0, stream>>>(feats, chart_p, chart_v, cfh, cfl, ln, n);
  }

  k_root<<<cB, 128, 0, stream>>>(chart_p, cfh, cfl, starts, out);
}

// Round 7
// 3534.171 us; speedup vs baseline: 4.5994x; 1.3031x over previous
//
#include <hip/hip_runtime.h>
#include <hip/hip_bf16.h>

// CYK forward. p-chain fp32; f-chain GEMM bf16x3 MFMA.
// Round 7: exploit chart_p quadrant support — O built on one 64x64 quadrant
// (4096 k) for middle diagonals only; d=0 / d=D-1 are rank-1 in a diag-0
// cell, served by precomputed e/f tables (128 MAC/row in k_normp).
// k_feats grid swapped for A-tile L2 reuse.

typedef __attribute__((ext_vector_type(8))) short short8;
typedef __attribute__((ext_vector_type(4))) float f32x4;

constexpr int cB = 64, cL = 32, cNT = 64, cS = 128, cV = 50000;
constexpr int cEMB = 512, cSD = 512, cKQ = 4096; // quadrant k
constexpr int DMAX = 31, KS = 32;                // k-slice = 128
constexpr float cEPS = 1e-9f;

__device__ __forceinline__ void split_bf16(float x, __hip_bfloat16& h, __hip_bfloat16& l) {
  h = __float2bfloat16(x);
  l = __float2bfloat16(x - __bfloat162float(h));
}

// ---------------- G quadrant permutes + Gsum2T ----------------
// Gll[p][a], p = s*64+t over (s,t)in[0,64)^2 ; Ghh likewise over [64,128)^2.
__global__ __launch_bounds__(256) void k_prep_g(const float* __restrict__ G,
                                                float* __restrict__ Gll,
                                                float* __restrict__ Ghh,
                                                float* __restrict__ GsumT) {
  int idx = blockIdx.x * 256 + threadIdx.x; // s*128+t
  int s = idx >> 7, t = idx & 127;
  bool lo = (s < 64) && (t < 64);
  bool hi = (s >= 64) && (t >= 64);
  int pl = s * 64 + t;                  // valid when lo
  int ph = (s - 64) * 64 + (t - 64);    // valid when hi
  float accum = 0.f;
  for (int a = 0; a < cNT; ++a) {
    float g = G[(size_t)a * 16384 + idx];
    accum += g;
    if (lo) Gll[(size_t)pl * cNT + a] = g;
    if (hi) Ghh[(size_t)ph * cNT + a] = g;
  }
  GsumT[t * cS + s] = accum;
}

// ---------------- WmT hi/lo split ----------------
__global__ __launch_bounds__(256) void k_prep_wmt(const float* __restrict__ Wm,
                                                  __hip_bfloat16* __restrict__ WmTh,
                                                  __hip_bfloat16* __restrict__ WmTl) {
  int idx = blockIdx.x * 256 + threadIdx.x; // n*1024 + k
  int k = idx & 1023, nn = idx >> 10;
  float v = Wm[(size_t)k * cSD + nn];
  __hip_bfloat16 h, l;
  split_bf16(v, h, l);
  WmTh[idx] = h;
  WmTl[idx] = l;
}

// ---------------- diagonal 0 of chart_p + chart_v ----------------
__global__ void k_diag(const int* __restrict__ word,
                       const float* __restrict__ preterm,
                       const float* __restrict__ GsumT,
                       float* __restrict__ chart_p,
                       float* __restrict__ chart_v) {
  __shared__ float ps[128];
  int row = blockIdx.x;  // cell = b*L + pos
  int tid = threadIdx.x; // 0..127
  int w = word[row];
  float val = (tid >= 64) ? preterm[(size_t)(tid - 64) * cV + w] : 0.f;
  float sum = val;
  #pragma unroll
  for (int off = 1; off < 64; off <<= 1) sum += __shfl_xor(sum, off, 64);
  float p_ = (tid >= 64) ? val / (sum + cEPS) : 0.f;
  size_t base = (size_t)row * cL * cS;
  chart_p[base + tid] = p_;
  ps[tid] = p_;
  __syncthreads();
  float v = 0.f;
  for (int t = 64; t < 128; ++t) v = fmaf(GsumT[t * cS + tid], ps[t], v);
  chart_v[base + tid] = v;
}

// ---------------- fp32 GEMM micro ----------------
__device__ __forceinline__ void micro16(const float (*As)[68], const float (*Bs)[68],
                                        int r0, int c0, float acc[4][4]) {
  #pragma unroll
  for (int k = 0; k < 16; ++k) {
    float4 a4 = *(const float4*)&As[k][r0];
    float4 b4 = *(const float4*)&Bs[k][c0];
    float ar[4] = {a4.x, a4.y, a4.z, a4.w};
    float br[4] = {b4.x, b4.y, b4.z, b4.w};
    #pragma unroll
    for (int i = 0; i < 4; ++i)
      #pragma unroll
      for (int j = 0; j < 4; ++j)
        acc[i][j] = fmaf(ar[i], br[j], acc[i][j]);
  }
}

// ---------------- e table: e[cell][a][t_lo] = sum_s p_hi[s] G[a][64+s][t] ----------------
// GEMM: M=2048 cells, N=4096 (c=a*64+t), K=64.
__global__ __launch_bounds__(256) void k_prep_e(const float* __restrict__ chart_p,
                                                const float* __restrict__ G,
                                                float* __restrict__ e_arr) {
  __shared__ float As[16][68];
  __shared__ float Bs[16][68];
  int tid = threadIdx.x;
  int rowTile = blockIdx.x * 64;
  int n0 = blockIdx.y * 64; // c-range = one a, t in [0,64)
  int a = n0 >> 6;
  int lr = tid >> 2, lk = (tid & 3) << 2;
  int bk = tid >> 4, bn = (tid & 15) << 2;
  int r0 = (tid >> 4) << 2, c0 = (tid & 15) << 2;
  float acc[4][4] = {};
  for (int kb = 0; kb < 64; kb += 16) {
    float4 av = *(const float4*)(chart_p + (size_t)(rowTile + lr) * 4096 + 64 + kb + lk);
    float4 bv = *(const float4*)(G + (size_t)a * 16384 + (size_t)(64 + kb + bk) * 128 + bn);
    __syncthreads();
    As[lk + 0][lr] = av.x; As[lk + 1][lr] = av.y;
    As[lk + 2][lr] = av.z; As[lk + 3][lr] = av.w;
    *(float4*)&Bs[bk][bn] = bv;
    __syncthreads();
    micro16(As, Bs, r0, c0, acc);
  }
  #pragma unroll
  for (int i = 0; i < 4; ++i) {
    float4 o = {acc[i][0], acc[i][1], acc[i][2], acc[i][3]};
    *(float4*)&e_arr[(size_t)(rowTile + r0 + i) * 4096 + n0 + c0] = o;
  }
}

// ---------------- f table: f[cell][a][s_lo] = sum_t G[a][s][64+t] p_hi[t] ----------------
// 8 cells per block to amortize the G quadrant read.
__global__ __launch_bounds__(256) void k_prep_f(const float* __restrict__ chart_p,
                                                const float* __restrict__ G,
                                                float* __restrict__ f_arr) {
  __shared__ float ph[8][64];
  int tid = threadIdx.x;
  int cell0 = blockIdx.x * 8;
  for (int v = tid; v < 512; v += 256) {
    int cc = v >> 6, t = v & 63;
    ph[cc][t] = chart_p[(size_t)(cell0 + cc) * 4096 + 64 + t];
  }
  __syncthreads();
  for (int oo = 0; oo < 16; ++oo) {
    int out_id = oo * 256 + tid; // a*64 + s
    int a = out_id >> 6, s = out_id & 63;
    const float* gb = G + (size_t)a * 16384 + (size_t)s * 128 + 64;
    float acc[8] = {};
    #pragma unroll 4
    for (int ch = 0; ch < 16; ++ch) {
      float4 g4 = *(const float4*)(gb + ch * 4);
      #pragma unroll
      for (int cc = 0; cc < 8; ++cc) {
        float4 p4 = *(const float4*)&ph[cc][ch * 4];
        acc[cc] = fmaf(g4.x, p4.x, acc[cc]);
        acc[cc] = fmaf(g4.y, p4.y, acc[cc]);
        acc[cc] = fmaf(g4.z, p4.z, acc[cc]);
        acc[cc] = fmaf(g4.w, p4.w, acc[cc]);
      }
    }
    #pragma unroll
    for (int cc = 0; cc < 8; ++cc)
      f_arr[(size_t)(cell0 + cc) * 4096 + out_id] = acc[cc];
  }
}

// ---------------- feat0 -> hi/lo planes ----------------
__global__ __launch_bounds__(256) void k_feat0(const int* __restrict__ word,
                                               const float* __restrict__ WE,
                                               const float* __restrict__ Wp,
                                               const float* __restrict__ bp,
                                               __hip_bfloat16* __restrict__ cfh,
                                               __hip_bfloat16* __restrict__ cfl) {
  __shared__ float As[16][68];
  __shared__ float Bs[16][68];
  int tid = threadIdx.x;
  int rowTile = blockIdx.x * 64;
  int n0 = blockIdx.y * 64;
  int lr = tid >> 2, lk = (tid & 3) << 2;
  int bk = tid >> 4, bn = (tid & 15) << 2;
  int r0 = (tid >> 4) << 2, c0 = (tid & 15) << 2;
  const float* ap = WE + (size_t)word[rowTile + lr] * cEMB;
  float acc[4][4] = {};
  for (int kb = 0; kb < cEMB; kb += 16) {
    float4 av = *(const float4*)(ap + kb + lk);
    float4 bv = *(const float4*)(Wp + (size_t)(kb + bk) * cSD + n0 + bn);
    __syncthreads();
    As[lk + 0][lr] = av.x; As[lk + 1][lr] = av.y;
    As[lk + 2][lr] = av.z; As[lk + 3][lr] = av.w;
    *(float4*)&Bs[bk][bn] = bv;
    __syncthreads();
    micro16(As, Bs, r0, c0, acc);
  }
  float4 bpv = *(const float4*)(bp + n0 + c0);
  float bpr[4] = {bpv.x, bpv.y, bpv.z, bpv.w};
  #pragma unroll
  for (int i = 0; i < 4; ++i) {
    int row = rowTile + r0 + i;
    size_t base = ((size_t)row * cL) * cSD + n0 + c0;
    #pragma unroll
    for (int e = 0; e < 4; ++e) {
      float v = fmaxf(acc[i][e] + bpr[e], 0.f);
      __hip_bfloat16 h, l;
      split_bf16(v, h, l);
      cfh[base + e] = h;
      cfl[base + e] = l;
    }
  }
}

// ---------------- feats GEMM bf16x3 MFMA (grid: x=col, y=row) ----------------
__global__ __launch_bounds__(256) void k_feats_mfma(
    const __hip_bfloat16* __restrict__ cfh, const __hip_bfloat16* __restrict__ cfl,
    const __hip_bfloat16* __restrict__ WmTh, const __hip_bfloat16* __restrict__ WmTl,
    const float* __restrict__ bm, float* __restrict__ feats, int ln, int n, int M) {
  __shared__ short Ash[2 * 128 * 40];
  __shared__ short Bsh[2 * 128 * 40];
  int tid = threadIdx.x;
  int Bn = cB * n;
  int rowTile = blockIdx.y * 128;
  int colTile = blockIdx.x * 128;
  int m0 = tid >> 2, kq8 = (tid & 3) * 8;

  long offA[2][2];
  #pragma unroll
  for (int h = 0; h < 2; ++h) {
    int row = rowTile + m0 + h * 64;
    if (row >= M) row = M - 1;
    int dd = row / Bn;
    int r = row - dd * Bn;
    int b = r / n, i = r - b * n;
    offA[h][0] = ((long)((b * cL + i) * cL + dd)) * cSD;
    offA[h][1] = ((long)((b * cL + i + dd + 1) * cL + (ln - dd - 2))) * cSD;
  }
  long offB0 = (long)(colTile + m0) * 1024;
  long offB1 = (long)(colTile + m0 + 64) * 1024;

  f32x4 acc[4][4];
  f32x4 zero = {0.f, 0.f, 0.f, 0.f};
  #pragma unroll
  for (int a_ = 0; a_ < 4; ++a_)
    #pragma unroll
    for (int b_ = 0; b_ < 4; ++b_) acc[a_][b_] = zero;

  int lane = tid & 63, wid = tid >> 6;
  int wm = wid >> 1, wn = wid & 1;
  int fr = lane & 15, fq = lane >> 4;

  int4 pA0h = *(const int4*)(const void*)(cfh + offA[0][0] + kq8);
  int4 pA1h = *(const int4*)(const void*)(cfh + offA[1][0] + kq8);
  int4 pA0l = *(const int4*)(const void*)(cfl + offA[0][0] + kq8);
  int4 pA1l = *(const int4*)(const void*)(cfl + offA[1][0] + kq8);
  int4 pB0h = *(const int4*)(const void*)(WmTh + offB0 + kq8);
  int4 pB1h = *(const int4*)(const void*)(WmTh + offB1 + kq8);
  int4 pB0l = *(const int4*)(const void*)(WmTl + offB0 + kq8);
  int4 pB1l = *(const int4*)(const void*)(WmTl + offB1 + kq8);

  for (int kb = 0; kb < 1024; kb += 32) {
    __syncthreads();
    *(int4*)&Ash[(0 * 128 + m0) * 40 + kq8] = pA0h;
    *(int4*)&Ash[(0 * 128 + m0 + 64) * 40 + kq8] = pA1h;
    *(int4*)&Ash[(1 * 128 + m0) * 40 + kq8] = pA0l;
    *(int4*)&Ash[(1 * 128 + m0 + 64) * 40 + kq8] = pA1l;
    *(int4*)&Bsh[(0 * 128 + m0) * 40 + kq8] = pB0h;
    *(int4*)&Bsh[(0 * 128 + m0 + 64) * 40 + kq8] = pB1h;
    *(int4*)&Bsh[(1 * 128 + m0) * 40 + kq8] = pB0l;
    *(int4*)&Bsh[(1 * 128 + m0 + 64) * 40 + kq8] = pB1l;
    __syncthreads();
    int kn = kb + 32;
    if (kn < 1024) {
      int sideL = (kn < cSD) ? 0 : 1;
      int klocal = kn - sideL * cSD;
      pA0h = *(const int4*)(const void*)(cfh + offA[0][sideL] + klocal + kq8);
      pA1h = *(const int4*)(const void*)(cfh + offA[1][sideL] + klocal + kq8);
      pA0l = *(const int4*)(const void*)(cfl + offA[0][sideL] + klocal + kq8);
      pA1l = *(const int4*)(const void*)(cfl + offA[1][sideL] + klocal + kq8);
      pB0h = *(const int4*)(const void*)(WmTh + offB0 + kn + kq8);
      pB1h = *(const int4*)(const void*)(WmTh + offB1 + kn + kq8);
      pB0l = *(const int4*)(const void*)(WmTl + offB0 + kn + kq8);
      pB1l = *(const int4*)(const void*)(WmTl + offB1 + kn + kq8);
    }
    short8 af[2][4], bf[2][4];
    #pragma unroll
    for (int pl = 0; pl < 2; ++pl)
      #pragma unroll
      for (int mf = 0; mf < 4; ++mf)
        af[pl][mf] = *(const short8*)&Ash[(pl * 128 + wm * 64 + mf * 16 + fr) * 40 + fq * 8];
    #pragma unroll
    for (int pl = 0; pl < 2; ++pl)
      #pragma unroll
      for (int nf = 0; nf < 4; ++nf)
        bf[pl][nf] = *(const short8*)&Bsh[(pl * 128 + wn * 64 + nf * 16 + fr) * 40 + fq * 8];
    #pragma unroll
    for (int mf = 0; mf < 4; ++mf)
      #pragma unroll
      for (int nf = 0; nf < 4; ++nf) {
        acc[mf][nf] = __builtin_amdgcn_mfma_f32_16x16x32_bf16(af[0][mf], bf[0][nf], acc[mf][nf], 0, 0, 0);
        acc[mf][nf] = __builtin_amdgcn_mfma_f32_16x16x32_bf16(af[0][mf], bf[1][nf], acc[mf][nf], 0, 0, 0);
        acc[mf][nf] = __builtin_amdgcn_mfma_f32_16x16x32_bf16(af[1][mf], bf[0][nf], acc[mf][nf], 0, 0, 0);
      }
  }
  #pragma unroll
  for (int mf = 0; mf < 4; ++mf)
    #pragma unroll
    for (int nf = 0; nf < 4; ++nf) {
      int col = colTile + wn * 64 + nf * 16 + fr;
      float bb = bm[col];
      #pragma unroll
      for (int r = 0; r < 4; ++r) {
        int row = rowTile + wm * 64 + mf * 16 + fq * 4 + r;
        feats[(size_t)row * cSD + col] = fmaxf(acc[mf][nf][r] + bb, 0.f);
      }
    }
}

// ---------------- quadrant outer-product: O[row][4096] over d-range ----------------
__global__ __launch_bounds__(256) void k_outer(const float* __restrict__ chart_p,
                                               float* __restrict__ O,
                                               int ln, int n, int chunkStart,
                                               int dlo, int dhi, int soff, int toff) {
  __shared__ float lp[DMAX][64];
  __shared__ float rp[DMAX][64];
  int tid = threadIdx.x;
  int row = chunkStart + blockIdx.x;
  int b = row / n, i = row - b * n;
  if (tid < 128) {
    int lane = tid & 63;
    for (int dd = dlo + (tid >> 6); dd <= dhi; dd += 2)
      lp[dd - dlo][lane] = chart_p[(((size_t)(b * cL + i)) * cL + dd) * cS + soff + lane];
  } else {
    int t2 = tid - 128;
    int lane = t2 & 63;
    for (int dd = dlo + (t2 >> 6); dd <= dhi; dd += 2)
      rp[dd - dlo][lane] =
          chart_p[(((size_t)(b * cL + i + dd + 1)) * cL + (ln - dd - 2)) * cS + toff + lane];
  }
  __syncthreads();
  float acc[16];
  #pragma unroll
  for (int j = 0; j < 16; ++j) acc[j] = 0.f;
  int s = tid >> 2, t0 = (tid & 3) << 4;
  int dcount = dhi - dlo + 1;
  for (int dd = 0; dd < dcount; ++dd) {
    float lps = lp[dd][s];
    #pragma unroll
    for (int qq = 0; qq < 4; ++qq) {
      float4 r4 = *(const float4*)&rp[dd][t0 + qq * 4];
      acc[qq * 4 + 0] = fmaf(lps, r4.x, acc[qq * 4 + 0]);
      acc[qq * 4 + 1] = fmaf(lps, r4.y, acc[qq * 4 + 1]);
      acc[qq * 4 + 2] = fmaf(lps, r4.z, acc[qq * 4 + 2]);
      acc[qq * 4 + 3] = fmaf(lps, r4.w, acc[qq * 4 + 3]);
    }
  }
  float* op = O + (size_t)blockIdx.x * cKQ + (size_t)tid * 16; // p = s*64+t
  #pragma unroll
  for (int j = 0; j < 4; ++j) {
    float4 o = {acc[j * 4 + 0], acc[j * 4 + 1], acc[j * 4 + 2], acc[j * 4 + 3]};
    *(float4*)&op[j * 4] = o;
  }
}

// ---------------- scores GEMM: O(CHx4096) @ Gq(4096x64), K-split 32 ----------------
__global__ __launch_bounds__(256) void k_scores(const float* __restrict__ O,
                                                const float* __restrict__ Gq,
                                                float* __restrict__ scoresP,
                                                int CHpad, int rows) {
  __shared__ float As[32][128];
  __shared__ float Bs[32][64];
  int tid = threadIdx.x;
  int rowTile = blockIdx.x * 128;
  int ks = blockIdx.y;       // 0..31
  int kstart = ks * 128;
  int sm = tid & 127, skq = (tid >> 7) * 16;
  int bq = tid >> 4, bn4 = (tid & 15) * 4;
  int m0 = (tid & 15) << 2, n0 = (tid >> 4) << 2;
  const float* ap = O + (size_t)(rowTile + sm) * cKQ + kstart + skq;
  float acc[8][4] = {};
  for (int kb = 0; kb < 128; kb += 32) {
    float4 a0 = *(const float4*)(ap + kb + 0);
    float4 a1 = *(const float4*)(ap + kb + 4);
    float4 a2 = *(const float4*)(ap + kb + 8);
    float4 a3 = *(const float4*)(ap + kb + 12);
    float4 b0 = *(const float4*)(Gq + (size_t)(kstart + kb + bq * 2) * cNT + bn4);
    float4 b1 = *(const float4*)(Gq + (size_t)(kstart + kb + bq * 2 + 1) * cNT + bn4);
    __syncthreads();
    As[skq + 0][sm] = a0.x; As[skq + 1][sm] = a0.y; As[skq + 2][sm] = a0.z; As[skq + 3][sm] = a0.w;
    As[skq + 4][sm] = a1.x; As[skq + 5][sm] = a1.y; As[skq + 6][sm] = a1.z; As[skq + 7][sm] = a1.w;
    As[skq + 8][sm] = a2.x; As[skq + 9][sm] = a2.y; As[skq + 10][sm] = a2.z; As[skq + 11][sm] = a2.w;
    As[skq + 12][sm] = a3.x; As[skq + 13][sm] = a3.y; As[skq + 14][sm] = a3.z; As[skq + 15][sm] = a3.w;
    *(float4*)&Bs[bq * 2][bn4] = b0;
    *(float4*)&Bs[bq * 2 + 1][bn4] = b1;
    __syncthreads();
    #pragma unroll
    for (int k = 0; k < 32; ++k) {
      float4 av0 = *(const float4*)&As[k][m0];
      float4 av1 = *(const float4*)&As[k][m0 + 64];
      float4 bv = *(const float4*)&Bs[k][n0];
      float ar[8] = {av0.x, av0.y, av0.z, av0.w, av1.x, av1.y, av1.z, av1.w};
      float br[4] = {bv.x, bv.y, bv.z, bv.w};
      #pragma unroll
      for (int i = 0; i < 8; ++i)
        #pragma unroll
        for (int j = 0; j < 4; ++j)
          acc[i][j] = fmaf(ar[i], br[j], acc[i][j]);
    }
  }
  #pragma unroll
  for (int i = 0; i < 8; ++i) {
    int row = rowTile + m0 + (i >> 2) * 64 + (i & 3);
    if (row < rows) {
      float4 o = {acc[i][0], acc[i][1], acc[i][2], acc[i][3]};
      *(float4*)&scoresP[((size_t)ks * CHpad + row) * cNT + n0] = o;
    }
  }
}

// ---------------- partial-reduce + e/f corrections + normalize + chart_v ----------------
__global__ void k_normp(const float* __restrict__ scoresP,
                        const float* __restrict__ e_arr,
                        const float* __restrict__ f_arr,
                        const float* __restrict__ GsumT,
                        float* __restrict__ chart_p,
                        float* __restrict__ chart_v,
                        int ln, int nn, int CHpad, int chunkStart,
                        int useGemm, int useEF) {
  __shared__ float sP[128]; // [0:64) rp_lo, [64:128) lp_lo
  __shared__ float ps[64];
  int lr = blockIdx.x;
  int tid = threadIdx.x; // 0..127
  int row = chunkStart + lr;
  int b = row / nn, i = row - b * nn;
  if (useEF) {
    if (tid < 64)
      sP[tid] = chart_p[(((size_t)(b * cL + i + 1)) * cL + (ln - 2)) * cS + tid];
    else
      sP[tid] = chart_p[(((size_t)(b * cL + i)) * cL + (ln - 2)) * cS + (tid - 64)];
    __syncthreads();
  }
  float val = 0.f;
  if (tid < 64) {
    if (useGemm)
      for (int ks = 0; ks < KS; ++ks)
        val += scoresP[((size_t)ks * CHpad + lr) * cNT + tid];
    if (useEF) {
      const float4* e4 = (const float4*)&e_arr[((size_t)(b * cL + i) * 4096) + tid * 64];
      const float4* f4 = (const float4*)&f_arr[((size_t)(b * cL + i + ln - 1) * 4096) + tid * 64];
      float ce = 0.f, cf = 0.f;
      #pragma unroll 4
      for (int q = 0; q < 16; ++q) {
        float4 ev = e4[q];
        float4 fv = f4[q];
        float4 rv = *(const float4*)&sP[q * 4];
        float4 lv = *(const float4*)&sP[64 + q * 4];
        ce = fmaf(ev.x, rv.x, ce); ce = fmaf(ev.y, rv.y, ce);
        ce = fmaf(ev.z, rv.z, ce); ce = fmaf(ev.w, rv.w, ce);
        cf = fmaf(fv.x, lv.x, cf); cf = fmaf(fv.y, lv.y, cf);
        cf = fmaf(fv.z, lv.z, cf); cf = fmaf(fv.w, lv.w, cf);
      }
      val += ce + cf;
    }
  }
  float sum = val;
  #pragma unroll
  for (int off = 1; off < 64; off <<= 1) sum += __shfl_xor(sum, off, 64);
  float p_ = (tid < 64) ? val / (sum + cEPS) : 0.f;
  size_t base = (((size_t)(b * cL + i)) * cL + (ln - 1)) * cS;
  chart_p[base + tid] = p_;
  if (tid < 64) ps[tid] = p_;
  __syncthreads();
  float v = 0.f;
  for (int t = 0; t < 64; ++t) v = fmaf(GsumT[t * cS + tid], ps[t], v);
  chart_v[base + tid] = v;
}

// ---------------- combine: masses via lp.v dots, weighted feats -> chart_f ----------------
__global__ __launch_bounds__(256) void k_combine(const float* __restrict__ feats,
                                                 const float* __restrict__ chart_p,
                                                 const float* __restrict__ chart_v,
                                                 __hip_bfloat16* __restrict__ cfh,
                                                 __hip_bfloat16* __restrict__ cfl,
                                                 int ln, int n) {
  __shared__ float lm[DMAX];
  __shared__ float red4[2][2];
  int row = blockIdx.x, tid = threadIdx.x;
  int D = ln - 1, Bn = cB * n;
  int b = row / n, i = row - b * n;
  int half = tid >> 7, l = tid & 127;
  for (int base0 = 0; base0 < D; base0 += 2) {
    int dd = base0 + half;
    float part = 0.f;
    if (dd < D) {
      size_t lpc = (((size_t)(b * cL + i)) * cL + dd) * cS;
      size_t vpc = (((size_t)(b * cL + i + dd + 1)) * cL + (ln - dd - 2)) * cS;
      part = chart_p[lpc + l] * chart_v[vpc + l];
    }
    #pragma unroll
    for (int off = 1; off < 64; off <<= 1) part += __shfl_xor(part, off, 64);
    if ((tid & 63) == 0) red4[half][(tid >> 6) & 1] = part;
    __syncthreads();
    if (tid < 2 && base0 + tid < D) lm[base0 + tid] = red4[tid][0] + red4[tid][1];
    __syncthreads();
  }
  float msum = 0.f;
  for (int dd = 0; dd < D; ++dd) msum += lm[dd];
  float inv = 1.f / (msum + cEPS);
  size_t outbase = (((size_t)(b * cL + i)) * cL + (ln - 1)) * cSD;
  for (int h = tid; h < cSD; h += 256) {
    float acc = 0.f;
    for (int dd = 0; dd < D; ++dd)
      acc = fmaf(lm[dd], feats[((size_t)dd * Bn + row) * cSD + h], acc);
    float v = acc * inv;
    __hip_bfloat16 hh, ll;
    split_bf16(v, hh, ll);
    cfh[outbase + h] = hh;
    cfl[outbase + h] = ll;
  }
}

// ---------------- root ----------------
__global__ void k_root(const float* __restrict__ chart_p,
                       const __hip_bfloat16* __restrict__ cfh,
                       const __hip_bfloat16* __restrict__ cfl,
                       const float* __restrict__ starts,
                       float* __restrict__ out) {
  __shared__ float red[2];
  int b = blockIdx.x, tid = threadIdx.x; // 128
  float v = chart_p[(((size_t)(b * cL)) * cL + (cL - 1)) * cS + tid] * starts[tid];
  #pragma unroll
  for (int off = 1; off < 64; off <<= 1) v += __shfl_xor(v, off, 64);
  if ((tid & 63) == 0) red[tid >> 6] = v;
  __syncthreads();
  float score = red[0] + red[1];
  size_t fbase = (((size_t)(b * cL)) * cL + (cL - 1)) * cSD;
  for (int h = tid; h < cSD; h += 128) {
    float f = __bfloat162float(cfh[fbase + h]) + __bfloat162float(cfl[fbase + h]);
    out[(size_t)b * cSD + h] = f * score;
  }
}

extern "C" void kernel_launch(void* const* d_in, const int* in_sizes, int n_in,
                              void* d_out, int out_size, void* d_ws, size_t ws_size,
                              hipStream_t stream) {
  const int* word = (const int*)d_in[0];
  const float* WE = (const float*)d_in[1];
  const float* preterm = (const float*)d_in[2];
  const float* G = (const float*)d_in[3];
  const float* starts = (const float*)d_in[4];
  const float* Wp = (const float*)d_in[5];
  const float* bp = (const float*)d_in[6];
  const float* Wm = (const float*)d_in[7];
  const float* bm = (const float*)d_in[8];
  float* out = (float*)d_out;
  float* ws = (float*)d_ws;

  size_t off = 0;
  float* chart_p = ws + off; off += (size_t)cB * cL * cL * cS;   // 33.5 MB
  float* chart_v = ws + off; off += (size_t)cB * cL * cL * cS;   // 33.5 MB
  __hip_bfloat16* cfh = (__hip_bfloat16*)(ws + off); off += (size_t)cB * cL * cL * cSD / 2;
  __hip_bfloat16* cfl = (__hip_bfloat16*)(ws + off); off += (size_t)cB * cL * cL * cSD / 2;
  float* Gll = ws + off; off += (size_t)cKQ * cNT;               // 1 MB
  float* Ghh = ws + off; off += (size_t)cKQ * cNT;               // 1 MB
  float* GsumT = ws + off; off += cS * cS;
  float* e_arr = ws + off; off += (size_t)2048 * 4096;           // 33.5 MB
  float* f_arr = ws + off; off += (size_t)2048 * 4096;           // 33.5 MB
  __hip_bfloat16* WmTh = (__hip_bfloat16*)(ws + off); off += (size_t)cSD * 1024 / 2;
  __hip_bfloat16* WmTl = (__hip_bfloat16*)(ws + off); off += (size_t)cSD * 1024 / 2;
  float* feats = ws + off; off += (size_t)16448 * cSD;           // 33.7 MB

  size_t avail = ws_size / sizeof(float) > off ? ws_size / sizeof(float) - off : 0;
  long perRow = cKQ + KS * cNT; // 6144 floats/row
  int CH = (int)(avail / perRow);
  if (CH > 1984) CH = 1984;
  CH &= ~127;
  if (CH < 128) CH = 128;
  int CHpad = CH;
  float* Obuf = ws + off; off += (size_t)CHpad * cKQ;
  float* scoresP = ws + off; off += (size_t)CHpad * KS * cNT;

  k_prep_g<<<(cS * cS) / 256, 256, 0, stream>>>(G, Gll, Ghh, GsumT);
  k_prep_wmt<<<(cSD * 1024) / 256, 256, 0, stream>>>(Wm, WmTh, WmTl);
  k_diag<<<cB * cL, 128, 0, stream>>>(word, preterm, GsumT, chart_p, chart_v);
  k_prep_e<<<dim3(2048 / 64, 4096 / 64), 256, 0, stream>>>(chart_p, G, e_arr);
  k_prep_f<<<2048 / 8, 256, 0, stream>>>(chart_p, G, f_arr);
  k_feat0<<<dim3((cB * cL) / 64, cSD / 64), 256, 0, stream>>>(word, WE, Wp, bp, cfh, cfl);

  for (int ln = 2; ln <= cL; ++ln) {
    int n = cL - ln + 1, D = ln - 1, Bn = cB * n;
    int M = D * Bn;
    int padM = (M + 127) & ~127;
    k_feats_mfma<<<dim3(cSD / 128, padM / 128), 256, 0, stream>>>(cfh, cfl, WmTh, WmTl, bm,
                                                                  feats, ln, n, M);
    int useGemm = (ln == 2 || ln >= 4) ? 1 : 0;
    int useEF = (ln >= 3) ? 1 : 0;
    for (int cs = 0; cs < Bn; cs += CH) {
      int rows = (Bn - cs) < CH ? (Bn - cs) : CH;
      int gx = (rows + 127) / 128;
      if (useGemm) {
        if (ln == 2)
          k_outer<<<rows, 256, 0, stream>>>(chart_p, Obuf, ln, n, cs, 0, 0, 64, 64);
        else
          k_outer<<<rows, 256, 0, stream>>>(chart_p, Obuf, ln, n, cs, 1, ln - 3, 0, 0);
        k_scores<<<dim3(gx, KS), 256, 0, stream>>>(Obuf, (ln == 2) ? Ghh : Gll,
                                                   scoresP, CHpad, rows);
      }
      k_normp<<<rows, 128, 0, stream>>>(scoresP, e_arr, f_arr, GsumT, chart_p, chart_v,
                                        ln, n, CHpad, cs, useGemm, useEF);
    }
    k_combine<<<Bn, 256, 0, stream>>>(feats, chart_p, chart_v, cfh, cfl, ln, n);
  }

  k_root<<<cB, 128, 0, stream>>>(chart_p, cfh, cfl, starts, out);
}